// Round 11
// baseline (346.115 us; speedup 1.0000x reference)
//
#include <hip/hip_runtime.h>
#include <hip/hip_bf16.h>

// SchNet forward on MI355X.
// W(d) -> 4096-bin nearest-neighbor bf16 table; ELL (packed col|bin) for
// atomic-free segment sum; telescoped linear residual (composed weights);
// bf16 MFMA GEMM; bf16 data plane.
// R11: revert R10's agg experiments (2-node/wave pairs loop bound to
//      max(dg1,dg2) ~ +22% iters; chmap adds a load to the dependent chain)
//      back to R9's proven 1-node/wave agg + materialized t1. New: readout
//      fused into agg2 (k_agg_ro): asum stays fp32 in registers/LDS, w_h
//      (16KB bf16) staged per grid-strided block -> kills readout dispatch,
//      asum 25MB round-trip, and whT buffer.

#define NN 50000      // nodes
#define NE 800000     // edges
#define NGR 512       // graphs
#define HD 128        // hidden
#define FD 128        // filters
#define GG 50         // gaussians
#define VOCAB 100
#define NB 4096       // table bins (nearest-neighbor)
#define DMAXT 12.0f   // table covers [0,12]
#define ELLS 80       // ELL stride; deg ~ Poisson(16)
#define SENT 50000u   // sentinel col -> zeroed extra row of t1/t2 (bin 0)
#define ASTR 136      // LDS row stride in bf16 elems

#define DELTA (10.0f/49.0f)
#define COEFF (-0.5f/(DELTA*DELTA))

// k_prep grid segments
#define TB_B 4096
#define WF_B 128
#define WH_B 64
#define TV_B 100
#define HG_B 100
#define BV_B 2
#define C4_B 391
#define Z_B  396      // ceil((NN+NGR+64+64)/128)
// k_embed_edge grid segments
#define EMBB 3125     // t1 gather: NN*16 uint4 / 256
#define EDGB 3125     // NE/256

typedef __attribute__((ext_vector_type(8))) short bf16x8;
typedef __attribute__((ext_vector_type(4))) float f32x4;

static __device__ __forceinline__ float sspf(float x) {
    return fmaxf(x, 0.0f) + log1pf(expf(-fabsf(x))) - 0.69314718055994531f;
}
static __device__ __forceinline__ float asf(unsigned int u) {
    union { unsigned int u; float f; } v; v.u = u; return v.f;
}
static __device__ __forceinline__ float bf2f(unsigned short b) {
    union { unsigned int u; float f; } v; v.u = ((unsigned int)b) << 16; return v.f;
}
static __device__ __forceinline__ unsigned short f2bf(float f) {
    union { float f; unsigned int u; } v; v.f = f;
    unsigned int r = v.u + 0x7FFF + ((v.u >> 16) & 1);   // round-nearest-even
    return (unsigned short)(r >> 16);
}

// Fused prep (segments by blockIdx.x): Tb table; wfT=(w_nm@w_el)^T;
// whf[k*64+o]=(w_nm@w_g1)[k][o]; tv=emb@w_el; hg=emb@w_g1; bv=b_nm@w_el,
// gvec=b_g1+2*b_nm@w_g1; coords->float4; zero deg/out/t1-/t2-sentinels.
__global__ __launch_bounds__(128) void k_prep(const float* __restrict__ w_e1,
                                              const float* __restrict__ b_e1,
                                              const float* __restrict__ w_e2,
                                              const float* __restrict__ b_e2,
                                              const float* __restrict__ w_el,
                                              const float* __restrict__ w_nm,
                                              const float* __restrict__ b_nm,
                                              const float* __restrict__ w_g1,
                                              const float* __restrict__ b_g1,
                                              const float* __restrict__ emb,
                                              const float* __restrict__ coords,
                                              unsigned int* __restrict__ Tb,
                                              unsigned short* __restrict__ wfT,
                                              unsigned short* __restrict__ whf,
                                              unsigned short* __restrict__ tv,
                                              unsigned short* __restrict__ hg,
                                              float* __restrict__ bv,
                                              float* __restrict__ gvec,
                                              float4* __restrict__ c4,
                                              int* __restrict__ deg,
                                              float* __restrict__ out,
                                              unsigned int* __restrict__ t1s,
                                              unsigned int* __restrict__ t2s) {
    __shared__ float sbuf[320];
    int bid = blockIdx.x, tx = threadIdx.x;
    if (bid < TB_B) {
        float* a = sbuf;            // 50
        float* y = sbuf + 64;       // 128
        float* z = sbuf + 192;      // 128
        float d = (float)bid * (DMAXT / (float)(NB - 1));
        if (tx < GG) {
            float o = (float)tx * DELTA;
            float tt = d - o;
            a[tx] = expf(COEFF * tt * tt);
        }
        __syncthreads();
        float acc = b_e1[tx];
        #pragma unroll 10
        for (int g = 0; g < GG; ++g) acc = fmaf(a[g], w_e1[g * FD + tx], acc);
        y[tx] = sspf(acc);
        __syncthreads();
        float acc2 = b_e2[tx];
        #pragma unroll 8
        for (int k = 0; k < FD; ++k) acc2 = fmaf(y[k], w_e2[k * FD + tx], acc2);
        z[tx] = acc2;
        __syncthreads();
        if (tx < 64)
            Tb[bid * 64 + tx] = (unsigned int)f2bf(z[2 * tx])
                              | ((unsigned int)f2bf(z[2 * tx + 1]) << 16);
    } else if (bid < TB_B + WF_B) {
        int n = bid - TB_B;
        sbuf[tx] = w_el[tx * 128 + n];
        __syncthreads();
        float acc = 0.f;
        #pragma unroll 8
        for (int j = 0; j < 128; ++j) acc = fmaf(w_nm[tx * 128 + j], sbuf[j], acc);
        wfT[n * 128 + tx] = f2bf(acc);
    } else if (bid < TB_B + WF_B + WH_B) {
        int n = bid - TB_B - WF_B;                // output col o (0..63)
        sbuf[tx] = w_g1[tx * 64 + n];
        __syncthreads();
        float acc = 0.f;
        #pragma unroll 8
        for (int j = 0; j < 128; ++j) acc = fmaf(w_nm[tx * 128 + j], sbuf[j], acc);
        whf[tx * 64 + n] = f2bf(acc);             // [k=tx][o=n]
    } else if (bid < TB_B + WF_B + WH_B + TV_B) {
        int r = bid - TB_B - WF_B - WH_B;
        sbuf[tx] = emb[r * HD + tx];
        __syncthreads();
        float acc = 0.f;
        #pragma unroll 8
        for (int k = 0; k < HD; ++k) acc = fmaf(sbuf[k], w_el[k * FD + tx], acc);
        tv[r * FD + tx] = f2bf(acc);
    } else if (bid < TB_B + WF_B + WH_B + TV_B + HG_B) {
        int c = bid - TB_B - WF_B - WH_B - TV_B;
        sbuf[tx] = emb[c * HD + tx];
        __syncthreads();
        if (tx < 64) {
            float acc = 0.f;
            #pragma unroll 8
            for (int k = 0; k < HD; ++k) acc = fmaf(sbuf[k], w_g1[k * 64 + tx], acc);
            hg[c * 64 + tx] = f2bf(acc);
        }
    } else if (bid < TB_B + WF_B + WH_B + TV_B + HG_B + BV_B) {
        int which = bid - (TB_B + WF_B + WH_B + TV_B + HG_B);
        if (which == 0) {
            float acc = 0.f;
            for (int k = 0; k < HD; ++k) acc = fmaf(b_nm[k], w_el[k * FD + tx], acc);
            bv[tx] = acc;
        } else if (tx < 64) {
            float acc = 0.f;
            for (int k = 0; k < HD; ++k) acc = fmaf(b_nm[k], w_g1[k * 64 + tx], acc);
            gvec[tx] = b_g1[tx] + 2.0f * acc;
        }
    } else if (bid < TB_B + WF_B + WH_B + TV_B + HG_B + BV_B + C4_B) {
        int i = (bid - (TB_B + WF_B + WH_B + TV_B + HG_B + BV_B)) * 128 + tx;
        if (i < NN)
            c4[i] = make_float4(coords[3 * i], coords[3 * i + 1],
                                coords[3 * i + 2], 0.f);
    } else {
        int j = (bid - (TB_B + WF_B + WH_B + TV_B + HG_B + BV_B + C4_B)) * 128 + tx;
        if (j < NN) deg[j] = 0;
        else if (j < NN + NGR) out[j - NN] = 0.f;
        else if (j < NN + NGR + 64) t1s[j - NN - NGR] = 0u;
        else if (j < NN + NGR + 128) t2s[j - NN - NGR - 64] = 0u;
    }
}

// Fused: [0,EMBB): t1[i] = tv[charges[i]]; [EMBB,+EDGB): edge bucketing.
__global__ __launch_bounds__(256) void k_embed_edge(const int* __restrict__ charges,
                                                    const unsigned short* __restrict__ tv,
                                                    const int* __restrict__ eidx,
                                                    const float4* __restrict__ c4,
                                                    unsigned short* __restrict__ t1,
                                                    int* __restrict__ deg,
                                                    unsigned int* __restrict__ emll) {
    int bid = blockIdx.x, tx = threadIdx.x;
    if (bid < EMBB) {
        int idx = bid * 256 + tx;      // exactly NN*16 uint4s
        int i = idx >> 4;
        int f = idx & 15;
        int c = charges[i];
        ((uint4*)t1)[(size_t)i * 16 + f] = ((const uint4*)tv)[(size_t)c * 16 + f];
    } else {
        int e = (bid - EMBB) * 256 + tx;   // exactly NE
        int r = eidx[e];
        int c = eidx[NE + e];
        float4 pr = c4[r], pc = c4[c];
        float dx = pr.x - pc.x, dy = pr.y - pc.y, dz = pr.z - pc.z;
        float d = sqrtf(dx * dx + dy * dy + dz * dz);
        float u = d * ((float)(NB - 1) / DMAXT);
        int b = (int)(u + 0.5f);
        if (b > NB - 1) b = NB - 1;
        unsigned int em = (unsigned int)c | ((unsigned int)b << 16);
        int pos = atomicAdd(&deg[r], 1);
        if (pos < ELLS) emll[r * ELLS + pos] = em;
    }
}

// LDS-staged MFMA GEMM: Out[M,128](bf16) = A(bf16) @ BT^T (+Cin bf16)(+bias f32).
__global__ __launch_bounds__(256) void k_gemm(const unsigned short* __restrict__ A,
                                              const unsigned short* __restrict__ BT,
                                              const unsigned short* __restrict__ Cin,
                                              const float* __restrict__ bias,
                                              unsigned short* __restrict__ Out,
                                              int M) {
    __shared__ unsigned short Als[64 * ASTR];    // 17.4 KB
    __shared__ unsigned short Bls[128 * ASTR];   // 34.8 KB
    int tx = threadIdx.x;
    int row0 = blockIdx.x * 64;
    #pragma unroll
    for (int q = 0; q < 4; ++q) {
        int l = tx + q * 256;
        int r = l >> 4, c = l & 15;
        int grow = row0 + r;
        uint4 v = make_uint4(0u, 0u, 0u, 0u);
        if (grow < M) v = *(const uint4*)(A + (size_t)grow * 128 + c * 8);
        *(uint4*)(&Als[r * ASTR + c * 8]) = v;
    }
    #pragma unroll
    for (int q = 0; q < 8; ++q) {
        int l = tx + q * 256;
        int r = l >> 4, c = l & 15;
        *(uint4*)(&Bls[r * ASTR + c * 8]) = *(const uint4*)(BT + (size_t)r * 128 + c * 8);
    }
    __syncthreads();

    int w = tx >> 6, lane = tx & 63, m = lane & 15, quad = lane >> 4;
    f32x4 acc[8];
    #pragma unroll
    for (int ct = 0; ct < 8; ++ct) acc[ct] = (f32x4){0.f, 0.f, 0.f, 0.f};
    #pragma unroll
    for (int s = 0; s < 4; ++s) {
        bf16x8 a = *(const bf16x8*)(&Als[(w * 16 + m) * ASTR + s * 32 + quad * 8]);
        #pragma unroll
        for (int ct = 0; ct < 8; ++ct) {
            bf16x8 b = *(const bf16x8*)(&Bls[(ct * 16 + m) * ASTR + s * 32 + quad * 8]);
            acc[ct] = __builtin_amdgcn_mfma_f32_16x16x32_bf16(a, b, acc[ct], 0, 0, 0);
        }
    }
    #pragma unroll
    for (int r = 0; r < 4; ++r) {
        int grow = row0 + w * 16 + quad * 4 + r;
        if (grow >= M) continue;
        #pragma unroll
        for (int ct = 0; ct < 8; ++ct) {
            int col = ct * 16 + m;
            float v = acc[ct][r];
            if (bias) v += bias[col];
            if (Cin)  v += bf2f(Cin[(size_t)grow * 128 + col]);
            Out[(size_t)grow * 128 + col] = f2bf(v);
        }
    }
}

// One wave per node: out[i,:] = sum_j t[col_j,:] * Tb[bin_j,:].
__global__ __launch_bounds__(256) void k_agg(const unsigned short* __restrict__ t,
                                             const unsigned int* __restrict__ Tb,
                                             const int* __restrict__ deg,
                                             const unsigned int* __restrict__ emll,
                                             unsigned short* __restrict__ outb) {
    int wave = (blockIdx.x * blockDim.x + threadIdx.x) >> 6;
    int lane = threadIdx.x & 63;
    if (wave >= NN) return;
    int dg = min(deg[wave], ELLS);
    int dgp = (dg + 7) & ~7;
    const int base = wave * ELLS;
    const unsigned short* tl = t + 2 * lane;
    const unsigned int* Tl = Tb + lane;
    float ax = 0.f, ay = 0.f;
    for (int j0 = 0; j0 < dgp; j0 += 64) {
        int n = min(64, dgp - j0);
        unsigned int myem = SENT;
        if (lane < dg - j0) myem = emll[base + j0 + lane];
        for (int j = 0; j < n; j += 8) {
            #pragma unroll
            for (int u = 0; u < 8; ++u) {
                unsigned int em = (unsigned int)__shfl((int)myem, j + u, 64);
                int c = em & 0xFFFF;
                int b = em >> 16;
                unsigned int tvv = *(const unsigned int*)(tl + (size_t)c * HD);
                unsigned int q = Tl[(size_t)b * 64];
                ax = fmaf(asf(tvv << 16), asf(q << 16), ax);
                ay = fmaf(asf(tvv & 0xFFFF0000u), asf(q & 0xFFFF0000u), ay);
            }
        }
    }
    unsigned int o = (unsigned int)f2bf(ax) | ((unsigned int)f2bf(ay) << 16);
    *(unsigned int*)(outb + (size_t)wave * FD + 2 * lane) = o;
}

// Fused agg2 + readout. Grid-strided: 3125 blocks x 4 waves x 4 iters = NN.
// Per node: asum row = AGG(t2) + agg1 (fp32, never stored); G1[o] =
// sum_k row[k]*w_h[k][o] + hg[ch][o] + gvec[o]; p = ssp(G1)@w_g2 + b_g2;
// atomicAdd(out[batch[node]], p). w_h 16KB bf16 in LDS, conflict-free reads.
__global__ __launch_bounds__(256) void k_agg_ro(const unsigned short* __restrict__ t,
                                                const unsigned int* __restrict__ Tb,
                                                const int* __restrict__ deg,
                                                const unsigned int* __restrict__ emll,
                                                const unsigned short* __restrict__ addin,
                                                const unsigned short* __restrict__ whf,
                                                const unsigned short* __restrict__ hg,
                                                const int* __restrict__ charges,
                                                const int* __restrict__ batch,
                                                const float* __restrict__ gvec,
                                                const float* __restrict__ w_g2,
                                                const float* __restrict__ b_g2,
                                                float* __restrict__ out) {
    __shared__ unsigned short whl[128 * 64];   // 16 KB
    __shared__ float rowb[4][128];             // 2 KB
    __shared__ float gv[64], wg[64];
    int tx = threadIdx.x;
    #pragma unroll
    for (int q = 0; q < 4; ++q) {              // stage w_h: 1024 uint4
        int l = tx + q * 256;
        ((uint4*)whl)[l] = ((const uint4*)whf)[l];
    }
    if (tx < 64) { gv[tx] = gvec[tx]; wg[tx] = w_g2[tx]; }
    __syncthreads();
    int wi = tx >> 6, lane = tx & 63;
    float bg2 = b_g2[0];
    const unsigned short* tl = t + 2 * lane;
    const unsigned int* Tl = Tb + lane;
    for (int it = 0; it < 4; ++it) {
        int node = it * 12500 + blockIdx.x * 4 + wi;
        int dg = min(deg[node], ELLS);
        int dgp = (dg + 7) & ~7;
        const int base = node * ELLS;
        float ax = 0.f, ay = 0.f;
        for (int j0 = 0; j0 < dgp; j0 += 64) {
            int n = min(64, dgp - j0);
            unsigned int myem = SENT;
            if (lane < dg - j0) myem = emll[base + j0 + lane];
            for (int j = 0; j < n; j += 8) {
                #pragma unroll
                for (int u = 0; u < 8; ++u) {
                    unsigned int em = (unsigned int)__shfl((int)myem, j + u, 64);
                    int c = em & 0xFFFF;
                    int b = em >> 16;
                    unsigned int tvv = *(const unsigned int*)(tl + (size_t)c * HD);
                    unsigned int q = Tl[(size_t)b * 64];
                    ax = fmaf(asf(tvv << 16), asf(q << 16), ax);
                    ay = fmaf(asf(tvv & 0xFFFF0000u), asf(q & 0xFFFF0000u), ay);
                }
            }
        }
        {
            unsigned int av = *(const unsigned int*)(addin + (size_t)node * FD + 2 * lane);
            ax += asf(av << 16);
            ay += asf(av & 0xFFFF0000u);
        }
        rowb[wi][2 * lane] = ax;
        rowb[wi][2 * lane + 1] = ay;
        __syncthreads();
        // lane o computes G1[o]
        float g1 = 0.f;
        #pragma unroll 8
        for (int k = 0; k < 128; ++k)
            g1 = fmaf(rowb[wi][k], bf2f(whl[k * 64 + lane]), g1);
        int ch = charges[node];
        g1 += bf2f(hg[ch * 64 + lane]) + gv[lane];
        float p = sspf(g1) * wg[lane];
        p += __shfl_down(p, 32, 64);
        p += __shfl_down(p, 16, 64);
        p += __shfl_down(p, 8, 64);
        p += __shfl_down(p, 4, 64);
        p += __shfl_down(p, 2, 64);
        p += __shfl_down(p, 1, 64);
        if (lane == 0) atomicAdd(&out[batch[node]], p + bg2);
        __syncthreads();
    }
}

extern "C" void kernel_launch(void* const* d_in, const int* in_sizes, int n_in,
                              void* d_out, int out_size, void* d_ws, size_t ws_size,
                              hipStream_t stream) {
    const int*   charges = (const int*)d_in[0];
    const float* coords  = (const float*)d_in[1];
    const int*   eidx    = (const int*)d_in[2];
    const int*   batch   = (const int*)d_in[3];
    const float* emb     = (const float*)d_in[4];
    const float* w_e1    = (const float*)d_in[5];
    const float* b_e1    = (const float*)d_in[6];
    const float* w_e2    = (const float*)d_in[7];
    const float* b_e2    = (const float*)d_in[8];
    const float* w_el    = (const float*)d_in[9];
    const float* w_nm    = (const float*)d_in[10];
    const float* b_nm    = (const float*)d_in[11];
    const float* w_g1    = (const float*)d_in[12];
    const float* b_g1    = (const float*)d_in[13];
    const float* w_g2    = (const float*)d_in[14];
    const float* b_g2    = (const float*)d_in[15];
    float* out = (float*)d_out;

    char* ws = (char*)d_ws;
    size_t off = 0;
    auto alloc = [&](size_t bytes) -> char* {
        char* p = ws + off;
        off += (bytes + 255) & ~(size_t)255;
        return p;
    };
    unsigned short* t1   = (unsigned short*)alloc((size_t)(NN + 1) * HD * 2); // +sentinel
    unsigned short* t2   = (unsigned short*)alloc((size_t)(NN + 1) * HD * 2); // +sentinel
    unsigned short* agg1 = (unsigned short*)alloc((size_t)NN * FD * 2);
    unsigned int*   Tb   = (unsigned int*)alloc((size_t)NB * 64 * 4);         // 1 MB
    int*            deg  = (int*)alloc((size_t)NN * 4);
    unsigned int*   emll = (unsigned int*)alloc((size_t)NN * ELLS * 4);       // 16 MB
    unsigned short* wfT  = (unsigned short*)alloc((size_t)128 * 128 * 2);
    unsigned short* whf  = (unsigned short*)alloc((size_t)128 * 64 * 2);      // 16 KB
    unsigned short* tv   = (unsigned short*)alloc((size_t)VOCAB * 128 * 2);
    unsigned short* hg   = (unsigned short*)alloc((size_t)VOCAB * 64 * 2);
    float*          bv   = (float*)alloc(128 * 4);
    float*          gvec = (float*)alloc(64 * 4);
    float4*         c4   = (float4*)alloc((size_t)NN * 16);
    if (off > ws_size) return;  // workspace too small -> fail visibly, no OOB

    k_prep<<<TB_B + WF_B + WH_B + TV_B + HG_B + BV_B + C4_B + Z_B, 128, 0, stream>>>(
        w_e1, b_e1, w_e2, b_e2, w_el, w_nm, b_nm, w_g1, b_g1, emb, coords,
        Tb, wfT, whf, tv, hg, bv, gvec, c4, deg, out,
        (unsigned int*)(t1 + (size_t)NN * HD),
        (unsigned int*)(t2 + (size_t)NN * HD));
    k_embed_edge<<<EMBB + EDGB, 256, 0, stream>>>(charges, tv, eidx, c4,
                                                  t1, deg, emll);

    // agg1 = AGG(t1)
    k_agg<<<NN / 4, 256, 0, stream>>>(t1, Tb, deg, emll, agg1);
    // t2 = t1 + agg1 @ w_f + b_nm@w_el
    k_gemm<<<(NN + 63) / 64, 256, 0, stream>>>(agg1, wfT, t1, bv, t2, NN);
    // fused: asum = agg1 + AGG(t2); out += readout(asum)
    k_agg_ro<<<3125, 256, 0, stream>>>(t2, Tb, deg, emll, agg1, whf, hg,
                                       charges, batch, gvec, w_g2, b_g2, out);
}

// Round 12
// 321.059 us; speedup vs baseline: 1.0780x; 1.0780x over previous
//
#include <hip/hip_runtime.h>
#include <hip/hip_bf16.h>

// SchNet forward on MI355X.
// W(d) -> 4096-bin nearest-neighbor table (fp32); ELL (packed col|bin) for
// atomic-free segment sum; telescoped linear residual (composed weights);
// bf16 MFMA GEMM; bf16 data plane.
// R12: revert to R9 structure (best: 284.6us; R10/R11 fusions both regressed).
//      Tweaks: (a) edge scatter standalone (R10 measured 50us vs 64 fused) +
//      tiny k_t1 streaming kernel; (b) table stored fp32 (L2-resident 2MB,
//      unpack-free float2 load, -2 VALU/edge in both aggs).

#define NN 50000      // nodes
#define NE 800000     // edges
#define NGR 512       // graphs
#define HD 128        // hidden
#define FD 128        // filters
#define GG 50         // gaussians
#define VOCAB 100
#define NB 4096       // table bins (nearest-neighbor)
#define DMAXT 12.0f   // table covers [0,12]
#define ELLS 80       // ELL stride; deg ~ Poisson(16)
#define SENT 50000u   // sentinel col -> zeroed extra row of t1/t2 (bin 0)
#define ASTR 136      // LDS row stride in bf16 elems

#define DELTA (10.0f/49.0f)
#define COEFF (-0.5f/(DELTA*DELTA))

// k_prep grid segments
#define TB_B 4096
#define WF_B 128
#define WH_B 64
#define TV_B 100
#define HG_B 100
#define BV_B 2
#define C4_B 391
#define Z_B  396      // ceil((NN+NGR+64+64)/128)

typedef __attribute__((ext_vector_type(8))) short bf16x8;
typedef __attribute__((ext_vector_type(4))) float f32x4;

static __device__ __forceinline__ float sspf(float x) {
    return fmaxf(x, 0.0f) + log1pf(expf(-fabsf(x))) - 0.69314718055994531f;
}
static __device__ __forceinline__ float asf(unsigned int u) {
    union { unsigned int u; float f; } v; v.u = u; return v.f;
}
static __device__ __forceinline__ float bf2f(unsigned short b) {
    union { unsigned int u; float f; } v; v.u = ((unsigned int)b) << 16; return v.f;
}
static __device__ __forceinline__ unsigned short f2bf(float f) {
    union { float f; unsigned int u; } v; v.f = f;
    unsigned int r = v.u + 0x7FFF + ((v.u >> 16) & 1);   // round-nearest-even
    return (unsigned short)(r >> 16);
}

// Fused prep (segments by blockIdx.x): Tbf table (fp32); wfT=(w_nm@w_el)^T;
// whT=(w_nm@w_g1)^T; tv=emb@w_el; hg=emb@w_g1; bv=b_nm@w_el,
// gvec=b_g1+2*b_nm@w_g1; coords->float4; zero deg/out/t1-/t2-sentinels.
__global__ __launch_bounds__(128) void k_prep(const float* __restrict__ w_e1,
                                              const float* __restrict__ b_e1,
                                              const float* __restrict__ w_e2,
                                              const float* __restrict__ b_e2,
                                              const float* __restrict__ w_el,
                                              const float* __restrict__ w_nm,
                                              const float* __restrict__ b_nm,
                                              const float* __restrict__ w_g1,
                                              const float* __restrict__ b_g1,
                                              const float* __restrict__ emb,
                                              const float* __restrict__ coords,
                                              float* __restrict__ Tbf,
                                              unsigned short* __restrict__ wfT,
                                              unsigned short* __restrict__ whT,
                                              unsigned short* __restrict__ tv,
                                              unsigned short* __restrict__ hg,
                                              float* __restrict__ bv,
                                              float* __restrict__ gvec,
                                              float4* __restrict__ c4,
                                              int* __restrict__ deg,
                                              float* __restrict__ out,
                                              unsigned int* __restrict__ t1s,
                                              unsigned int* __restrict__ t2s) {
    __shared__ float sbuf[192];
    int bid = blockIdx.x, tx = threadIdx.x;
    if (bid < TB_B) {
        float* a = sbuf;            // 50
        float* y = sbuf + 64;       // 128
        float d = (float)bid * (DMAXT / (float)(NB - 1));
        if (tx < GG) {
            float o = (float)tx * DELTA;
            float tt = d - o;
            a[tx] = expf(COEFF * tt * tt);
        }
        __syncthreads();
        float acc = b_e1[tx];
        #pragma unroll 10
        for (int g = 0; g < GG; ++g) acc = fmaf(a[g], w_e1[g * FD + tx], acc);
        y[tx] = sspf(acc);
        __syncthreads();
        float acc2 = b_e2[tx];
        #pragma unroll 8
        for (int k = 0; k < FD; ++k) acc2 = fmaf(y[k], w_e2[k * FD + tx], acc2);
        Tbf[bid * 128 + tx] = acc2;
    } else if (bid < TB_B + WF_B) {
        int n = bid - TB_B;
        sbuf[tx] = w_el[tx * 128 + n];
        __syncthreads();
        float acc = 0.f;
        #pragma unroll 8
        for (int j = 0; j < 128; ++j) acc = fmaf(w_nm[tx * 128 + j], sbuf[j], acc);
        wfT[n * 128 + tx] = f2bf(acc);
    } else if (bid < TB_B + WF_B + WH_B) {
        int n = bid - TB_B - WF_B;                // output col (0..63)
        sbuf[tx] = w_g1[tx * 64 + n];
        __syncthreads();
        float acc = 0.f;
        #pragma unroll 8
        for (int j = 0; j < 128; ++j) acc = fmaf(w_nm[tx * 128 + j], sbuf[j], acc);
        whT[n * 128 + tx] = f2bf(acc);            // [n][k] B-fragment layout
    } else if (bid < TB_B + WF_B + WH_B + TV_B) {
        int r = bid - TB_B - WF_B - WH_B;
        sbuf[tx] = emb[r * HD + tx];
        __syncthreads();
        float acc = 0.f;
        #pragma unroll 8
        for (int k = 0; k < HD; ++k) acc = fmaf(sbuf[k], w_el[k * FD + tx], acc);
        tv[r * FD + tx] = f2bf(acc);
    } else if (bid < TB_B + WF_B + WH_B + TV_B + HG_B) {
        int c = bid - TB_B - WF_B - WH_B - TV_B;
        sbuf[tx] = emb[c * HD + tx];
        __syncthreads();
        if (tx < 64) {
            float acc = 0.f;
            #pragma unroll 8
            for (int k = 0; k < HD; ++k) acc = fmaf(sbuf[k], w_g1[k * 64 + tx], acc);
            hg[c * 64 + tx] = f2bf(acc);
        }
    } else if (bid < TB_B + WF_B + WH_B + TV_B + HG_B + BV_B) {
        int which = bid - (TB_B + WF_B + WH_B + TV_B + HG_B);
        if (which == 0) {
            float acc = 0.f;
            for (int k = 0; k < HD; ++k) acc = fmaf(b_nm[k], w_el[k * FD + tx], acc);
            bv[tx] = acc;
        } else if (tx < 64) {
            float acc = 0.f;
            for (int k = 0; k < HD; ++k) acc = fmaf(b_nm[k], w_g1[k * 64 + tx], acc);
            gvec[tx] = b_g1[tx] + 2.0f * acc;
        }
    } else if (bid < TB_B + WF_B + WH_B + TV_B + HG_B + BV_B + C4_B) {
        int i = (bid - (TB_B + WF_B + WH_B + TV_B + HG_B + BV_B)) * 128 + tx;
        if (i < NN)
            c4[i] = make_float4(coords[3 * i], coords[3 * i + 1],
                                coords[3 * i + 2], 0.f);
    } else {
        int j = (bid - (TB_B + WF_B + WH_B + TV_B + HG_B + BV_B + C4_B)) * 128 + tx;
        if (j < NN) deg[j] = 0;
        else if (j < NN + NGR) out[j - NN] = 0.f;
        else if (j < NN + NGR + 64) t1s[j - NN - NGR] = 0u;
        else if (j < NN + NGR + 128) t2s[j - NN - NGR - 64] = 0u;
    }
}

// t1[i] = tv[charges[i]]  (pure streaming gather from 25.6KB hot table)
__global__ __launch_bounds__(256) void k_t1(const int* __restrict__ charges,
                                            const unsigned short* __restrict__ tv,
                                            unsigned short* __restrict__ t1) {
    int idx = blockIdx.x * 256 + threadIdx.x;   // exactly NN*16 uint4s
    int i = idx >> 4;
    int f = idx & 15;
    int c = charges[i];
    ((uint4*)t1)[(size_t)i * 16 + f] = ((const uint4*)tv)[(size_t)c * 16 + f];
}

// Edge bucketing: pack (col 16b | bin 12b) into ELL slot of row.
__global__ __launch_bounds__(256) void k_edge(const int* __restrict__ eidx,
                                              const float4* __restrict__ c4,
                                              int* __restrict__ deg,
                                              unsigned int* __restrict__ emll) {
    int e = blockIdx.x * 256 + threadIdx.x;     // exactly NE
    int r = eidx[e];
    int c = eidx[NE + e];
    float4 pr = c4[r], pc = c4[c];
    float dx = pr.x - pc.x, dy = pr.y - pc.y, dz = pr.z - pc.z;
    float d = sqrtf(dx * dx + dy * dy + dz * dz);
    float u = d * ((float)(NB - 1) / DMAXT);
    int b = (int)(u + 0.5f);
    if (b > NB - 1) b = NB - 1;
    unsigned int em = (unsigned int)c | ((unsigned int)b << 16);
    int pos = atomicAdd(&deg[r], 1);
    if (pos < ELLS) emll[r * ELLS + pos] = em;
}

// LDS-staged MFMA GEMM: Out[M,128](bf16) = A(bf16) @ BT^T (+Cin bf16)(+bias f32).
__global__ __launch_bounds__(256) void k_gemm(const unsigned short* __restrict__ A,
                                              const unsigned short* __restrict__ BT,
                                              const unsigned short* __restrict__ Cin,
                                              const float* __restrict__ bias,
                                              unsigned short* __restrict__ Out,
                                              int M) {
    __shared__ unsigned short Als[64 * ASTR];    // 17.4 KB
    __shared__ unsigned short Bls[128 * ASTR];   // 34.8 KB
    int tx = threadIdx.x;
    int row0 = blockIdx.x * 64;
    #pragma unroll
    for (int q = 0; q < 4; ++q) {
        int l = tx + q * 256;
        int r = l >> 4, c = l & 15;
        int grow = row0 + r;
        uint4 v = make_uint4(0u, 0u, 0u, 0u);
        if (grow < M) v = *(const uint4*)(A + (size_t)grow * 128 + c * 8);
        *(uint4*)(&Als[r * ASTR + c * 8]) = v;
    }
    #pragma unroll
    for (int q = 0; q < 8; ++q) {
        int l = tx + q * 256;
        int r = l >> 4, c = l & 15;
        *(uint4*)(&Bls[r * ASTR + c * 8]) = *(const uint4*)(BT + (size_t)r * 128 + c * 8);
    }
    __syncthreads();

    int w = tx >> 6, lane = tx & 63, m = lane & 15, quad = lane >> 4;
    f32x4 acc[8];
    #pragma unroll
    for (int ct = 0; ct < 8; ++ct) acc[ct] = (f32x4){0.f, 0.f, 0.f, 0.f};
    #pragma unroll
    for (int s = 0; s < 4; ++s) {
        bf16x8 a = *(const bf16x8*)(&Als[(w * 16 + m) * ASTR + s * 32 + quad * 8]);
        #pragma unroll
        for (int ct = 0; ct < 8; ++ct) {
            bf16x8 b = *(const bf16x8*)(&Bls[(ct * 16 + m) * ASTR + s * 32 + quad * 8]);
            acc[ct] = __builtin_amdgcn_mfma_f32_16x16x32_bf16(a, b, acc[ct], 0, 0, 0);
        }
    }
    #pragma unroll
    for (int r = 0; r < 4; ++r) {
        int grow = row0 + w * 16 + quad * 4 + r;
        if (grow >= M) continue;
        #pragma unroll
        for (int ct = 0; ct < 8; ++ct) {
            int col = ct * 16 + m;
            float v = acc[ct][r];
            if (bias) v += bias[col];
            if (Cin)  v += bf2f(Cin[(size_t)grow * 128 + col]);
            Out[(size_t)grow * 128 + col] = f2bf(v);
        }
    }
}

// One wave per node: out[i,:] = sum_j t[col_j,:] * Tbf[bin_j,:] (+ addin[i,:]).
// Per edge: 1 shfl + 4B t-gather + 8B fp32 table load + 2 unpack + 2 FMA.
__global__ __launch_bounds__(256) void k_agg(const unsigned short* __restrict__ t,
                                             const float* __restrict__ Tbf,
                                             const int* __restrict__ deg,
                                             const unsigned int* __restrict__ emll,
                                             const unsigned short* __restrict__ addin,
                                             unsigned short* __restrict__ outb) {
    int wave = (blockIdx.x * blockDim.x + threadIdx.x) >> 6;
    int lane = threadIdx.x & 63;
    if (wave >= NN) return;
    int dg = min(deg[wave], ELLS);
    int dgp = (dg + 7) & ~7;
    const int base = wave * ELLS;
    const unsigned short* tl = t + 2 * lane;
    const float* Tl = Tbf + 2 * lane;
    float ax = 0.f, ay = 0.f;
    for (int j0 = 0; j0 < dgp; j0 += 64) {
        int n = min(64, dgp - j0);
        unsigned int myem = SENT;
        if (lane < dg - j0) myem = emll[base + j0 + lane];
        for (int j = 0; j < n; j += 8) {
            #pragma unroll
            for (int u = 0; u < 8; ++u) {
                unsigned int em = (unsigned int)__shfl((int)myem, j + u, 64);
                int c = em & 0xFFFF;
                int b = em >> 16;
                unsigned int tvv = *(const unsigned int*)(tl + (size_t)c * HD);
                float2 q = *(const float2*)(Tl + (size_t)b * 128);
                ax = fmaf(asf(tvv << 16), q.x, ax);
                ay = fmaf(asf(tvv & 0xFFFF0000u), q.y, ay);
            }
        }
    }
    if (addin) {
        unsigned int av = *(const unsigned int*)(addin + (size_t)wave * FD + 2 * lane);
        ax += asf(av << 16);
        ay += asf(av & 0xFFFF0000u);
    }
    unsigned int o = (unsigned int)f2bf(ax) | ((unsigned int)f2bf(ay) << 16);
    *(unsigned int*)(outb + (size_t)wave * FD + 2 * lane) = o;
}

// Readout: G1 = asum@w_h + hg[charge[row]] + gvec; p = ssp(G1)@w_g2 + b_g2;
// atomicAdd(out[batch[row]], p).
__global__ __launch_bounds__(256) void k_readout(const unsigned short* __restrict__ asum,
                                                 const int* __restrict__ charges,
                                                 const int* __restrict__ batch,
                                                 const unsigned short* __restrict__ whT,
                                                 const unsigned short* __restrict__ hg,
                                                 const float* __restrict__ gvec,
                                                 const float* __restrict__ w_g2,
                                                 const float* __restrict__ b_g2,
                                                 float* __restrict__ out) {
    __shared__ unsigned short Als[64 * ASTR];
    __shared__ unsigned short Bls[64 * ASTR];
    int tx = threadIdx.x;
    int row0 = blockIdx.x * 64;
    #pragma unroll
    for (int q = 0; q < 4; ++q) {
        int l = tx + q * 256;
        int r = l >> 4, c = l & 15;
        int grow = row0 + r;
        uint4 v = make_uint4(0u, 0u, 0u, 0u);
        if (grow < NN) v = *(const uint4*)(asum + (size_t)grow * 128 + c * 8);
        *(uint4*)(&Als[r * ASTR + c * 8]) = v;
    }
    #pragma unroll
    for (int q = 0; q < 4; ++q) {
        int l = tx + q * 256;
        int r = l >> 4, c = l & 15;
        *(uint4*)(&Bls[r * ASTR + c * 8]) = *(const uint4*)(whT + (size_t)r * 128 + c * 8);
    }
    __syncthreads();

    int w = tx >> 6, lane = tx & 63, m = lane & 15, quad = lane >> 4;
    f32x4 acc[4];
    #pragma unroll
    for (int ct = 0; ct < 4; ++ct) acc[ct] = (f32x4){0.f, 0.f, 0.f, 0.f};
    #pragma unroll
    for (int s = 0; s < 4; ++s) {
        bf16x8 a = *(const bf16x8*)(&Als[(w * 16 + m) * ASTR + s * 32 + quad * 8]);
        #pragma unroll
        for (int ct = 0; ct < 4; ++ct) {
            bf16x8 b = *(const bf16x8*)(&Bls[(ct * 16 + m) * ASTR + s * 32 + quad * 8]);
            acc[ct] = __builtin_amdgcn_mfma_f32_16x16x32_bf16(a, b, acc[ct], 0, 0, 0);
        }
    }
    float gv[4], w2[4];
    #pragma unroll
    for (int ct = 0; ct < 4; ++ct) {
        int col = ct * 16 + m;
        gv[ct] = gvec[col];
        w2[ct] = w_g2[col];
    }
    float bg2 = b_g2[0];
    #pragma unroll
    for (int r = 0; r < 4; ++r) {
        int row = row0 + w * 16 + quad * 4 + r;
        int rowc = row < NN ? row : NN - 1;
        int ch = charges[rowc];
        float p = 0.f;
        #pragma unroll
        for (int ct = 0; ct < 4; ++ct) {
            int col = ct * 16 + m;
            float g1 = acc[ct][r] + bf2f(hg[ch * 64 + col]) + gv[ct];
            p += sspf(g1) * w2[ct];
        }
        p += __shfl_down(p, 8, 16);
        p += __shfl_down(p, 4, 16);
        p += __shfl_down(p, 2, 16);
        p += __shfl_down(p, 1, 16);
        if (m == 0 && row < NN) atomicAdd(&out[batch[row]], p + bg2);
    }
}

extern "C" void kernel_launch(void* const* d_in, const int* in_sizes, int n_in,
                              void* d_out, int out_size, void* d_ws, size_t ws_size,
                              hipStream_t stream) {
    const int*   charges = (const int*)d_in[0];
    const float* coords  = (const float*)d_in[1];
    const int*   eidx    = (const int*)d_in[2];
    const int*   batch   = (const int*)d_in[3];
    const float* emb     = (const float*)d_in[4];
    const float* w_e1    = (const float*)d_in[5];
    const float* b_e1    = (const float*)d_in[6];
    const float* w_e2    = (const float*)d_in[7];
    const float* b_e2    = (const float*)d_in[8];
    const float* w_el    = (const float*)d_in[9];
    const float* w_nm    = (const float*)d_in[10];
    const float* b_nm    = (const float*)d_in[11];
    const float* w_g1    = (const float*)d_in[12];
    const float* b_g1    = (const float*)d_in[13];
    const float* w_g2    = (const float*)d_in[14];
    const float* b_g2    = (const float*)d_in[15];
    float* out = (float*)d_out;

    char* ws = (char*)d_ws;
    size_t off = 0;
    auto alloc = [&](size_t bytes) -> char* {
        char* p = ws + off;
        off += (bytes + 255) & ~(size_t)255;
        return p;
    };
    unsigned short* t1   = (unsigned short*)alloc((size_t)(NN + 1) * HD * 2); // +sentinel
    unsigned short* t2   = (unsigned short*)alloc((size_t)(NN + 1) * HD * 2); // +sentinel
    unsigned short* agg1 = (unsigned short*)alloc((size_t)NN * FD * 2);
    unsigned short* asum = (unsigned short*)alloc((size_t)NN * FD * 2);
    float*          Tbf  = (float*)alloc((size_t)NB * 128 * 4);               // 2 MB
    int*            deg  = (int*)alloc((size_t)NN * 4);
    unsigned int*   emll = (unsigned int*)alloc((size_t)NN * ELLS * 4);       // 16 MB
    unsigned short* wfT  = (unsigned short*)alloc((size_t)128 * 128 * 2);
    unsigned short* whT  = (unsigned short*)alloc((size_t)64 * 128 * 2);
    unsigned short* tv   = (unsigned short*)alloc((size_t)VOCAB * 128 * 2);
    unsigned short* hg   = (unsigned short*)alloc((size_t)VOCAB * 64 * 2);
    float*          bv   = (float*)alloc(128 * 4);
    float*          gvec = (float*)alloc(64 * 4);
    float4*         c4   = (float4*)alloc((size_t)NN * 16);
    if (off > ws_size) return;  // workspace too small -> fail visibly, no OOB

    k_prep<<<TB_B + WF_B + WH_B + TV_B + HG_B + BV_B + C4_B + Z_B, 128, 0, stream>>>(
        w_e1, b_e1, w_e2, b_e2, w_el, w_nm, b_nm, w_g1, b_g1, emb, coords,
        Tbf, wfT, whT, tv, hg, bv, gvec, c4, deg, out,
        (unsigned int*)(t1 + (size_t)NN * HD),
        (unsigned int*)(t2 + (size_t)NN * HD));
    k_t1<<<NN * 16 / 256, 256, 0, stream>>>(charges, tv, t1);
    k_edge<<<NE / 256, 256, 0, stream>>>(eidx, c4, deg, emll);

    // agg1 = AGG(t1)
    k_agg<<<NN / 4, 256, 0, stream>>>(t1, Tbf, deg, emll, nullptr, agg1);
    // t2 = t1 + agg1 @ w_f + b_nm@w_el
    k_gemm<<<(NN + 63) / 64, 256, 0, stream>>>(agg1, wfT, t1, bv, t2, NN);
    // asum = agg1 + AGG(t2)
    k_agg<<<NN / 4, 256, 0, stream>>>(t2, Tbf, deg, emll, agg1, asum);

    k_readout<<<(NN + 63) / 64, 256, 0, stream>>>(asum, charges, batch, whT, hg,
                                                  gvec, w_g2, b_g2, out);
}

// Round 13
// 289.968 us; speedup vs baseline: 1.1936x; 1.1072x over previous
//
#include <hip/hip_runtime.h>
#include <hip/hip_bf16.h>

// SchNet forward on MI355X.
// W(d) -> 4096-bin nearest-neighbor bf16-packed table; ELL (packed col|bin)
// for atomic-free segment sum; telescoped linear residual (composed weights);
// bf16 MFMA GEMM; bf16 data plane.
// R13: best-of-measured config. R9 kernels exactly (bf16 Tb table: R12's fp32
//      table regressed agg FETCH 83->118MB; 1-node/wave agg: R10/R11 variants
//      regressed) + R12's standalone k_edge/k_t1 split (52+4 vs 64 fused).

#define NN 50000      // nodes
#define NE 800000     // edges
#define NGR 512       // graphs
#define HD 128        // hidden
#define FD 128        // filters
#define GG 50         // gaussians
#define VOCAB 100
#define NB 4096       // table bins (nearest-neighbor)
#define DMAXT 12.0f   // table covers [0,12]
#define ELLS 80       // ELL stride; deg ~ Poisson(16)
#define SENT 50000u   // sentinel col -> zeroed extra row of t1/t2 (bin 0)
#define ASTR 136      // LDS row stride in bf16 elems

#define DELTA (10.0f/49.0f)
#define COEFF (-0.5f/(DELTA*DELTA))

// k_prep grid segments
#define TB_B 4096
#define WF_B 128
#define WH_B 64
#define TV_B 100
#define HG_B 100
#define BV_B 2
#define C4_B 391
#define Z_B  396      // ceil((NN+NGR+64+64)/128)

typedef __attribute__((ext_vector_type(8))) short bf16x8;
typedef __attribute__((ext_vector_type(4))) float f32x4;

static __device__ __forceinline__ float sspf(float x) {
    return fmaxf(x, 0.0f) + log1pf(expf(-fabsf(x))) - 0.69314718055994531f;
}
static __device__ __forceinline__ float asf(unsigned int u) {
    union { unsigned int u; float f; } v; v.u = u; return v.f;
}
static __device__ __forceinline__ float bf2f(unsigned short b) {
    union { unsigned int u; float f; } v; v.u = ((unsigned int)b) << 16; return v.f;
}
static __device__ __forceinline__ unsigned short f2bf(float f) {
    union { float f; unsigned int u; } v; v.f = f;
    unsigned int r = v.u + 0x7FFF + ((v.u >> 16) & 1);   // round-nearest-even
    return (unsigned short)(r >> 16);
}

// Fused prep (segments by blockIdx.x): Tb bf16-packed table; wfT=(w_nm@w_el)^T;
// whT=(w_nm@w_g1)^T; tv=emb@w_el; hg=emb@w_g1; bv=b_nm@w_el,
// gvec=b_g1+2*b_nm@w_g1; coords->float4; zero deg/out/t1-/t2-sentinels.
__global__ __launch_bounds__(128) void k_prep(const float* __restrict__ w_e1,
                                              const float* __restrict__ b_e1,
                                              const float* __restrict__ w_e2,
                                              const float* __restrict__ b_e2,
                                              const float* __restrict__ w_el,
                                              const float* __restrict__ w_nm,
                                              const float* __restrict__ b_nm,
                                              const float* __restrict__ w_g1,
                                              const float* __restrict__ b_g1,
                                              const float* __restrict__ emb,
                                              const float* __restrict__ coords,
                                              unsigned int* __restrict__ Tb,
                                              unsigned short* __restrict__ wfT,
                                              unsigned short* __restrict__ whT,
                                              unsigned short* __restrict__ tv,
                                              unsigned short* __restrict__ hg,
                                              float* __restrict__ bv,
                                              float* __restrict__ gvec,
                                              float4* __restrict__ c4,
                                              int* __restrict__ deg,
                                              float* __restrict__ out,
                                              unsigned int* __restrict__ t1s,
                                              unsigned int* __restrict__ t2s) {
    __shared__ float sbuf[320];
    int bid = blockIdx.x, tx = threadIdx.x;
    if (bid < TB_B) {
        float* a = sbuf;            // 50
        float* y = sbuf + 64;       // 128
        float* z = sbuf + 192;      // 128
        float d = (float)bid * (DMAXT / (float)(NB - 1));
        if (tx < GG) {
            float o = (float)tx * DELTA;
            float tt = d - o;
            a[tx] = expf(COEFF * tt * tt);
        }
        __syncthreads();
        float acc = b_e1[tx];
        #pragma unroll 10
        for (int g = 0; g < GG; ++g) acc = fmaf(a[g], w_e1[g * FD + tx], acc);
        y[tx] = sspf(acc);
        __syncthreads();
        float acc2 = b_e2[tx];
        #pragma unroll 8
        for (int k = 0; k < FD; ++k) acc2 = fmaf(y[k], w_e2[k * FD + tx], acc2);
        z[tx] = acc2;
        __syncthreads();
        if (tx < 64)
            Tb[bid * 64 + tx] = (unsigned int)f2bf(z[2 * tx])
                              | ((unsigned int)f2bf(z[2 * tx + 1]) << 16);
    } else if (bid < TB_B + WF_B) {
        int n = bid - TB_B;
        sbuf[tx] = w_el[tx * 128 + n];
        __syncthreads();
        float acc = 0.f;
        #pragma unroll 8
        for (int j = 0; j < 128; ++j) acc = fmaf(w_nm[tx * 128 + j], sbuf[j], acc);
        wfT[n * 128 + tx] = f2bf(acc);
    } else if (bid < TB_B + WF_B + WH_B) {
        int n = bid - TB_B - WF_B;                // output col (0..63)
        sbuf[tx] = w_g1[tx * 64 + n];
        __syncthreads();
        float acc = 0.f;
        #pragma unroll 8
        for (int j = 0; j < 128; ++j) acc = fmaf(w_nm[tx * 128 + j], sbuf[j], acc);
        whT[n * 128 + tx] = f2bf(acc);            // [n][k] B-fragment layout
    } else if (bid < TB_B + WF_B + WH_B + TV_B) {
        int r = bid - TB_B - WF_B - WH_B;
        sbuf[tx] = emb[r * HD + tx];
        __syncthreads();
        float acc = 0.f;
        #pragma unroll 8
        for (int k = 0; k < HD; ++k) acc = fmaf(sbuf[k], w_el[k * FD + tx], acc);
        tv[r * FD + tx] = f2bf(acc);
    } else if (bid < TB_B + WF_B + WH_B + TV_B + HG_B) {
        int c = bid - TB_B - WF_B - WH_B - TV_B;
        sbuf[tx] = emb[c * HD + tx];
        __syncthreads();
        if (tx < 64) {
            float acc = 0.f;
            #pragma unroll 8
            for (int k = 0; k < HD; ++k) acc = fmaf(sbuf[k], w_g1[k * 64 + tx], acc);
            hg[c * 64 + tx] = f2bf(acc);
        }
    } else if (bid < TB_B + WF_B + WH_B + TV_B + HG_B + BV_B) {
        int which = bid - (TB_B + WF_B + WH_B + TV_B + HG_B);
        if (which == 0) {
            float acc = 0.f;
            for (int k = 0; k < HD; ++k) acc = fmaf(b_nm[k], w_el[k * FD + tx], acc);
            bv[tx] = acc;
        } else if (tx < 64) {
            float acc = 0.f;
            for (int k = 0; k < HD; ++k) acc = fmaf(b_nm[k], w_g1[k * 64 + tx], acc);
            gvec[tx] = b_g1[tx] + 2.0f * acc;
        }
    } else if (bid < TB_B + WF_B + WH_B + TV_B + HG_B + BV_B + C4_B) {
        int i = (bid - (TB_B + WF_B + WH_B + TV_B + HG_B + BV_B)) * 128 + tx;
        if (i < NN)
            c4[i] = make_float4(coords[3 * i], coords[3 * i + 1],
                                coords[3 * i + 2], 0.f);
    } else {
        int j = (bid - (TB_B + WF_B + WH_B + TV_B + HG_B + BV_B + C4_B)) * 128 + tx;
        if (j < NN) deg[j] = 0;
        else if (j < NN + NGR) out[j - NN] = 0.f;
        else if (j < NN + NGR + 64) t1s[j - NN - NGR] = 0u;
        else if (j < NN + NGR + 128) t2s[j - NN - NGR - 64] = 0u;
    }
}

// t1[i] = tv[charges[i]]  (pure streaming gather from 25.6KB hot table)
__global__ __launch_bounds__(256) void k_t1(const int* __restrict__ charges,
                                            const unsigned short* __restrict__ tv,
                                            unsigned short* __restrict__ t1) {
    int idx = blockIdx.x * 256 + threadIdx.x;   // exactly NN*16 uint4s
    int i = idx >> 4;
    int f = idx & 15;
    int c = charges[i];
    ((uint4*)t1)[(size_t)i * 16 + f] = ((const uint4*)tv)[(size_t)c * 16 + f];
}

// Edge bucketing: pack (col 16b | bin 12b) into ELL slot of row.
__global__ __launch_bounds__(256) void k_edge(const int* __restrict__ eidx,
                                              const float4* __restrict__ c4,
                                              int* __restrict__ deg,
                                              unsigned int* __restrict__ emll) {
    int e = blockIdx.x * 256 + threadIdx.x;     // exactly NE
    int r = eidx[e];
    int c = eidx[NE + e];
    float4 pr = c4[r], pc = c4[c];
    float dx = pr.x - pc.x, dy = pr.y - pc.y, dz = pr.z - pc.z;
    float d = sqrtf(dx * dx + dy * dy + dz * dz);
    float u = d * ((float)(NB - 1) / DMAXT);
    int b = (int)(u + 0.5f);
    if (b > NB - 1) b = NB - 1;
    unsigned int em = (unsigned int)c | ((unsigned int)b << 16);
    int pos = atomicAdd(&deg[r], 1);
    if (pos < ELLS) emll[r * ELLS + pos] = em;
}

// LDS-staged MFMA GEMM: Out[M,128](bf16) = A(bf16) @ BT^T (+Cin bf16)(+bias f32).
__global__ __launch_bounds__(256) void k_gemm(const unsigned short* __restrict__ A,
                                              const unsigned short* __restrict__ BT,
                                              const unsigned short* __restrict__ Cin,
                                              const float* __restrict__ bias,
                                              unsigned short* __restrict__ Out,
                                              int M) {
    __shared__ unsigned short Als[64 * ASTR];    // 17.4 KB
    __shared__ unsigned short Bls[128 * ASTR];   // 34.8 KB
    int tx = threadIdx.x;
    int row0 = blockIdx.x * 64;
    #pragma unroll
    for (int q = 0; q < 4; ++q) {
        int l = tx + q * 256;
        int r = l >> 4, c = l & 15;
        int grow = row0 + r;
        uint4 v = make_uint4(0u, 0u, 0u, 0u);
        if (grow < M) v = *(const uint4*)(A + (size_t)grow * 128 + c * 8);
        *(uint4*)(&Als[r * ASTR + c * 8]) = v;
    }
    #pragma unroll
    for (int q = 0; q < 8; ++q) {
        int l = tx + q * 256;
        int r = l >> 4, c = l & 15;
        *(uint4*)(&Bls[r * ASTR + c * 8]) = *(const uint4*)(BT + (size_t)r * 128 + c * 8);
    }
    __syncthreads();

    int w = tx >> 6, lane = tx & 63, m = lane & 15, quad = lane >> 4;
    f32x4 acc[8];
    #pragma unroll
    for (int ct = 0; ct < 8; ++ct) acc[ct] = (f32x4){0.f, 0.f, 0.f, 0.f};
    #pragma unroll
    for (int s = 0; s < 4; ++s) {
        bf16x8 a = *(const bf16x8*)(&Als[(w * 16 + m) * ASTR + s * 32 + quad * 8]);
        #pragma unroll
        for (int ct = 0; ct < 8; ++ct) {
            bf16x8 b = *(const bf16x8*)(&Bls[(ct * 16 + m) * ASTR + s * 32 + quad * 8]);
            acc[ct] = __builtin_amdgcn_mfma_f32_16x16x32_bf16(a, b, acc[ct], 0, 0, 0);
        }
    }
    #pragma unroll
    for (int r = 0; r < 4; ++r) {
        int grow = row0 + w * 16 + quad * 4 + r;
        if (grow >= M) continue;
        #pragma unroll
        for (int ct = 0; ct < 8; ++ct) {
            int col = ct * 16 + m;
            float v = acc[ct][r];
            if (bias) v += bias[col];
            if (Cin)  v += bf2f(Cin[(size_t)grow * 128 + col]);
            Out[(size_t)grow * 128 + col] = f2bf(v);
        }
    }
}

// One wave per node: out[i,:] = sum_j t[col_j,:] * Tb[bin_j,:] (+ addin[i,:]).
// Per edge: 1 shfl + 4B t-gather + 4B packed-bf16 table load + 2 FMA.
__global__ __launch_bounds__(256) void k_agg(const unsigned short* __restrict__ t,
                                             const unsigned int* __restrict__ Tb,
                                             const int* __restrict__ deg,
                                             const unsigned int* __restrict__ emll,
                                             const unsigned short* __restrict__ addin,
                                             unsigned short* __restrict__ outb) {
    int wave = (blockIdx.x * blockDim.x + threadIdx.x) >> 6;
    int lane = threadIdx.x & 63;
    if (wave >= NN) return;
    int dg = min(deg[wave], ELLS);
    int dgp = (dg + 7) & ~7;
    const int base = wave * ELLS;
    const unsigned short* tl = t + 2 * lane;
    const unsigned int* Tl = Tb + lane;
    float ax = 0.f, ay = 0.f;
    if (addin) {   // hoisted: issues early, overlaps the gather loop
        unsigned int av = *(const unsigned int*)(addin + (size_t)wave * FD + 2 * lane);
        ax = asf(av << 16);
        ay = asf(av & 0xFFFF0000u);
    }
    for (int j0 = 0; j0 < dgp; j0 += 64) {
        int n = min(64, dgp - j0);
        unsigned int myem = SENT;
        if (lane < dg - j0) myem = emll[base + j0 + lane];
        for (int j = 0; j < n; j += 8) {
            #pragma unroll
            for (int u = 0; u < 8; ++u) {
                unsigned int em = (unsigned int)__shfl((int)myem, j + u, 64);
                int c = em & 0xFFFF;
                int b = em >> 16;
                unsigned int tvv = *(const unsigned int*)(tl + (size_t)c * HD);
                unsigned int q = Tl[(size_t)b * 64];
                ax = fmaf(asf(tvv << 16), asf(q << 16), ax);
                ay = fmaf(asf(tvv & 0xFFFF0000u), asf(q & 0xFFFF0000u), ay);
            }
        }
    }
    unsigned int o = (unsigned int)f2bf(ax) | ((unsigned int)f2bf(ay) << 16);
    *(unsigned int*)(outb + (size_t)wave * FD + 2 * lane) = o;
}

// Readout: G1 = asum@w_h + hg[charge[row]] + gvec; p = ssp(G1)@w_g2 + b_g2;
// atomicAdd(out[batch[row]], p).
__global__ __launch_bounds__(256) void k_readout(const unsigned short* __restrict__ asum,
                                                 const int* __restrict__ charges,
                                                 const int* __restrict__ batch,
                                                 const unsigned short* __restrict__ whT,
                                                 const unsigned short* __restrict__ hg,
                                                 const float* __restrict__ gvec,
                                                 const float* __restrict__ w_g2,
                                                 const float* __restrict__ b_g2,
                                                 float* __restrict__ out) {
    __shared__ unsigned short Als[64 * ASTR];
    __shared__ unsigned short Bls[64 * ASTR];
    int tx = threadIdx.x;
    int row0 = blockIdx.x * 64;
    #pragma unroll
    for (int q = 0; q < 4; ++q) {
        int l = tx + q * 256;
        int r = l >> 4, c = l & 15;
        int grow = row0 + r;
        uint4 v = make_uint4(0u, 0u, 0u, 0u);
        if (grow < NN) v = *(const uint4*)(asum + (size_t)grow * 128 + c * 8);
        *(uint4*)(&Als[r * ASTR + c * 8]) = v;
    }
    #pragma unroll
    for (int q = 0; q < 4; ++q) {
        int l = tx + q * 256;
        int r = l >> 4, c = l & 15;
        *(uint4*)(&Bls[r * ASTR + c * 8]) = *(const uint4*)(whT + (size_t)r * 128 + c * 8);
    }
    __syncthreads();

    int w = tx >> 6, lane = tx & 63, m = lane & 15, quad = lane >> 4;
    f32x4 acc[4];
    #pragma unroll
    for (int ct = 0; ct < 4; ++ct) acc[ct] = (f32x4){0.f, 0.f, 0.f, 0.f};
    #pragma unroll
    for (int s = 0; s < 4; ++s) {
        bf16x8 a = *(const bf16x8*)(&Als[(w * 16 + m) * ASTR + s * 32 + quad * 8]);
        #pragma unroll
        for (int ct = 0; ct < 4; ++ct) {
            bf16x8 b = *(const bf16x8*)(&Bls[(ct * 16 + m) * ASTR + s * 32 + quad * 8]);
            acc[ct] = __builtin_amdgcn_mfma_f32_16x16x32_bf16(a, b, acc[ct], 0, 0, 0);
        }
    }
    float gv[4], w2[4];
    #pragma unroll
    for (int ct = 0; ct < 4; ++ct) {
        int col = ct * 16 + m;
        gv[ct] = gvec[col];
        w2[ct] = w_g2[col];
    }
    float bg2 = b_g2[0];
    #pragma unroll
    for (int r = 0; r < 4; ++r) {
        int row = row0 + w * 16 + quad * 4 + r;
        int rowc = row < NN ? row : NN - 1;
        int ch = charges[rowc];
        float p = 0.f;
        #pragma unroll
        for (int ct = 0; ct < 4; ++ct) {
            int col = ct * 16 + m;
            float g1 = acc[ct][r] + bf2f(hg[ch * 64 + col]) + gv[ct];
            p += sspf(g1) * w2[ct];
        }
        p += __shfl_down(p, 8, 16);
        p += __shfl_down(p, 4, 16);
        p += __shfl_down(p, 2, 16);
        p += __shfl_down(p, 1, 16);
        if (m == 0 && row < NN) atomicAdd(&out[batch[row]], p + bg2);
    }
}

extern "C" void kernel_launch(void* const* d_in, const int* in_sizes, int n_in,
                              void* d_out, int out_size, void* d_ws, size_t ws_size,
                              hipStream_t stream) {
    const int*   charges = (const int*)d_in[0];
    const float* coords  = (const float*)d_in[1];
    const int*   eidx    = (const int*)d_in[2];
    const int*   batch   = (const int*)d_in[3];
    const float* emb     = (const float*)d_in[4];
    const float* w_e1    = (const float*)d_in[5];
    const float* b_e1    = (const float*)d_in[6];
    const float* w_e2    = (const float*)d_in[7];
    const float* b_e2    = (const float*)d_in[8];
    const float* w_el    = (const float*)d_in[9];
    const float* w_nm    = (const float*)d_in[10];
    const float* b_nm    = (const float*)d_in[11];
    const float* w_g1    = (const float*)d_in[12];
    const float* b_g1    = (const float*)d_in[13];
    const float* w_g2    = (const float*)d_in[14];
    const float* b_g2    = (const float*)d_in[15];
    float* out = (float*)d_out;

    char* ws = (char*)d_ws;
    size_t off = 0;
    auto alloc = [&](size_t bytes) -> char* {
        char* p = ws + off;
        off += (bytes + 255) & ~(size_t)255;
        return p;
    };
    unsigned short* t1   = (unsigned short*)alloc((size_t)(NN + 1) * HD * 2); // +sentinel
    unsigned short* t2   = (unsigned short*)alloc((size_t)(NN + 1) * HD * 2); // +sentinel
    unsigned short* agg1 = (unsigned short*)alloc((size_t)NN * FD * 2);
    unsigned short* asum = (unsigned short*)alloc((size_t)NN * FD * 2);
    unsigned int*   Tb   = (unsigned int*)alloc((size_t)NB * 64 * 4);         // 1 MB
    int*            deg  = (int*)alloc((size_t)NN * 4);
    unsigned int*   emll = (unsigned int*)alloc((size_t)NN * ELLS * 4);       // 16 MB
    unsigned short* wfT  = (unsigned short*)alloc((size_t)128 * 128 * 2);
    unsigned short* whT  = (unsigned short*)alloc((size_t)64 * 128 * 2);
    unsigned short* tv   = (unsigned short*)alloc((size_t)VOCAB * 128 * 2);
    unsigned short* hg   = (unsigned short*)alloc((size_t)VOCAB * 64 * 2);
    float*          bv   = (float*)alloc(128 * 4);
    float*          gvec = (float*)alloc(64 * 4);
    float4*         c4   = (float4*)alloc((size_t)NN * 16);
    if (off > ws_size) return;  // workspace too small -> fail visibly, no OOB

    k_prep<<<TB_B + WF_B + WH_B + TV_B + HG_B + BV_B + C4_B + Z_B, 128, 0, stream>>>(
        w_e1, b_e1, w_e2, b_e2, w_el, w_nm, b_nm, w_g1, b_g1, emb, coords,
        Tb, wfT, whT, tv, hg, bv, gvec, c4, deg, out,
        (unsigned int*)(t1 + (size_t)NN * HD),
        (unsigned int*)(t2 + (size_t)NN * HD));
    k_t1<<<NN * 16 / 256, 256, 0, stream>>>(charges, tv, t1);
    k_edge<<<NE / 256, 256, 0, stream>>>(eidx, c4, deg, emll);

    // agg1 = AGG(t1)
    k_agg<<<NN / 4, 256, 0, stream>>>(t1, Tb, deg, emll, nullptr, agg1);
    // t2 = t1 + agg1 @ w_f + b_nm@w_el
    k_gemm<<<(NN + 63) / 64, 256, 0, stream>>>(agg1, wfT, t1, bv, t2, NN);
    // asum = agg1 + AGG(t2)
    k_agg<<<NN / 4, 256, 0, stream>>>(t2, Tb, deg, emll, agg1, asum);

    k_readout<<<(NN + 63) / 64, 256, 0, stream>>>(asum, charges, batch, whT, hg,
                                                  gvec, w_g2, b_g2, out);
}

// Round 14
// 260.420 us; speedup vs baseline: 1.3291x; 1.1135x over previous
//
#include <hip/hip_runtime.h>
#include <hip/hip_bf16.h>

// SchNet forward on MI355X.
// W(d) -> 4096-bin nearest-neighbor bf16-packed table; ELL (packed col|bin)
// for atomic-free segment sum; telescoped linear residual (composed weights);
// bf16 MFMA GEMM; bf16 data plane.
// R14: R13 + readout atomic fix. rocprof showed k_readout ~50us with all
//      pipes idle: 50k device-scope atomicAdds onto 512 floats (32 lines)
//      ping-ponging across 8 XCDs. batch is SORTED -> block-level segmented
//      scan (LDS + 6-step shuffle) emits ~1 atomic per graph per block
//      (~2k total, 25x fewer).

#define NN 50000      // nodes
#define NE 800000     // edges
#define NGR 512       // graphs
#define HD 128        // hidden
#define FD 128        // filters
#define GG 50         // gaussians
#define VOCAB 100
#define NB 4096       // table bins (nearest-neighbor)
#define DMAXT 12.0f   // table covers [0,12]
#define ELLS 80       // ELL stride; deg ~ Poisson(16)
#define SENT 50000u   // sentinel col -> zeroed extra row of t1/t2 (bin 0)
#define ASTR 136      // LDS row stride in bf16 elems

#define DELTA (10.0f/49.0f)
#define COEFF (-0.5f/(DELTA*DELTA))

// k_prep grid segments
#define TB_B 4096
#define WF_B 128
#define WH_B 64
#define TV_B 100
#define HG_B 100
#define BV_B 2
#define C4_B 391
#define Z_B  396      // ceil((NN+NGR+64+64)/128)

typedef __attribute__((ext_vector_type(8))) short bf16x8;
typedef __attribute__((ext_vector_type(4))) float f32x4;

static __device__ __forceinline__ float sspf(float x) {
    return fmaxf(x, 0.0f) + log1pf(expf(-fabsf(x))) - 0.69314718055994531f;
}
static __device__ __forceinline__ float asf(unsigned int u) {
    union { unsigned int u; float f; } v; v.u = u; return v.f;
}
static __device__ __forceinline__ float bf2f(unsigned short b) {
    union { unsigned int u; float f; } v; v.u = ((unsigned int)b) << 16; return v.f;
}
static __device__ __forceinline__ unsigned short f2bf(float f) {
    union { float f; unsigned int u; } v; v.f = f;
    unsigned int r = v.u + 0x7FFF + ((v.u >> 16) & 1);   // round-nearest-even
    return (unsigned short)(r >> 16);
}

// Fused prep (segments by blockIdx.x): Tb bf16-packed table; wfT=(w_nm@w_el)^T;
// whT=(w_nm@w_g1)^T; tv=emb@w_el; hg=emb@w_g1; bv=b_nm@w_el,
// gvec=b_g1+2*b_nm@w_g1; coords->float4; zero deg/out/t1-/t2-sentinels.
__global__ __launch_bounds__(128) void k_prep(const float* __restrict__ w_e1,
                                              const float* __restrict__ b_e1,
                                              const float* __restrict__ w_e2,
                                              const float* __restrict__ b_e2,
                                              const float* __restrict__ w_el,
                                              const float* __restrict__ w_nm,
                                              const float* __restrict__ b_nm,
                                              const float* __restrict__ w_g1,
                                              const float* __restrict__ b_g1,
                                              const float* __restrict__ emb,
                                              const float* __restrict__ coords,
                                              unsigned int* __restrict__ Tb,
                                              unsigned short* __restrict__ wfT,
                                              unsigned short* __restrict__ whT,
                                              unsigned short* __restrict__ tv,
                                              unsigned short* __restrict__ hg,
                                              float* __restrict__ bv,
                                              float* __restrict__ gvec,
                                              float4* __restrict__ c4,
                                              int* __restrict__ deg,
                                              float* __restrict__ out,
                                              unsigned int* __restrict__ t1s,
                                              unsigned int* __restrict__ t2s) {
    __shared__ float sbuf[320];
    int bid = blockIdx.x, tx = threadIdx.x;
    if (bid < TB_B) {
        float* a = sbuf;            // 50
        float* y = sbuf + 64;       // 128
        float* z = sbuf + 192;      // 128
        float d = (float)bid * (DMAXT / (float)(NB - 1));
        if (tx < GG) {
            float o = (float)tx * DELTA;
            float tt = d - o;
            a[tx] = expf(COEFF * tt * tt);
        }
        __syncthreads();
        float acc = b_e1[tx];
        #pragma unroll 10
        for (int g = 0; g < GG; ++g) acc = fmaf(a[g], w_e1[g * FD + tx], acc);
        y[tx] = sspf(acc);
        __syncthreads();
        float acc2 = b_e2[tx];
        #pragma unroll 8
        for (int k = 0; k < FD; ++k) acc2 = fmaf(y[k], w_e2[k * FD + tx], acc2);
        z[tx] = acc2;
        __syncthreads();
        if (tx < 64)
            Tb[bid * 64 + tx] = (unsigned int)f2bf(z[2 * tx])
                              | ((unsigned int)f2bf(z[2 * tx + 1]) << 16);
    } else if (bid < TB_B + WF_B) {
        int n = bid - TB_B;
        sbuf[tx] = w_el[tx * 128 + n];
        __syncthreads();
        float acc = 0.f;
        #pragma unroll 8
        for (int j = 0; j < 128; ++j) acc = fmaf(w_nm[tx * 128 + j], sbuf[j], acc);
        wfT[n * 128 + tx] = f2bf(acc);
    } else if (bid < TB_B + WF_B + WH_B) {
        int n = bid - TB_B - WF_B;                // output col (0..63)
        sbuf[tx] = w_g1[tx * 64 + n];
        __syncthreads();
        float acc = 0.f;
        #pragma unroll 8
        for (int j = 0; j < 128; ++j) acc = fmaf(w_nm[tx * 128 + j], sbuf[j], acc);
        whT[n * 128 + tx] = f2bf(acc);            // [n][k] B-fragment layout
    } else if (bid < TB_B + WF_B + WH_B + TV_B) {
        int r = bid - TB_B - WF_B - WH_B;
        sbuf[tx] = emb[r * HD + tx];
        __syncthreads();
        float acc = 0.f;
        #pragma unroll 8
        for (int k = 0; k < HD; ++k) acc = fmaf(sbuf[k], w_el[k * FD + tx], acc);
        tv[r * FD + tx] = f2bf(acc);
    } else if (bid < TB_B + WF_B + WH_B + TV_B + HG_B) {
        int c = bid - TB_B - WF_B - WH_B - TV_B;
        sbuf[tx] = emb[c * HD + tx];
        __syncthreads();
        if (tx < 64) {
            float acc = 0.f;
            #pragma unroll 8
            for (int k = 0; k < HD; ++k) acc = fmaf(sbuf[k], w_g1[k * 64 + tx], acc);
            hg[c * 64 + tx] = f2bf(acc);
        }
    } else if (bid < TB_B + WF_B + WH_B + TV_B + HG_B + BV_B) {
        int which = bid - (TB_B + WF_B + WH_B + TV_B + HG_B);
        if (which == 0) {
            float acc = 0.f;
            for (int k = 0; k < HD; ++k) acc = fmaf(b_nm[k], w_el[k * FD + tx], acc);
            bv[tx] = acc;
        } else if (tx < 64) {
            float acc = 0.f;
            for (int k = 0; k < HD; ++k) acc = fmaf(b_nm[k], w_g1[k * 64 + tx], acc);
            gvec[tx] = b_g1[tx] + 2.0f * acc;
        }
    } else if (bid < TB_B + WF_B + WH_B + TV_B + HG_B + BV_B + C4_B) {
        int i = (bid - (TB_B + WF_B + WH_B + TV_B + HG_B + BV_B)) * 128 + tx;
        if (i < NN)
            c4[i] = make_float4(coords[3 * i], coords[3 * i + 1],
                                coords[3 * i + 2], 0.f);
    } else {
        int j = (bid - (TB_B + WF_B + WH_B + TV_B + HG_B + BV_B + C4_B)) * 128 + tx;
        if (j < NN) deg[j] = 0;
        else if (j < NN + NGR) out[j - NN] = 0.f;
        else if (j < NN + NGR + 64) t1s[j - NN - NGR] = 0u;
        else if (j < NN + NGR + 128) t2s[j - NN - NGR - 64] = 0u;
    }
}

// t1[i] = tv[charges[i]]  (pure streaming gather from 25.6KB hot table)
__global__ __launch_bounds__(256) void k_t1(const int* __restrict__ charges,
                                            const unsigned short* __restrict__ tv,
                                            unsigned short* __restrict__ t1) {
    int idx = blockIdx.x * 256 + threadIdx.x;   // exactly NN*16 uint4s
    int i = idx >> 4;
    int f = idx & 15;
    int c = charges[i];
    ((uint4*)t1)[(size_t)i * 16 + f] = ((const uint4*)tv)[(size_t)c * 16 + f];
}

// Edge bucketing: pack (col 16b | bin 12b) into ELL slot of row.
__global__ __launch_bounds__(256) void k_edge(const int* __restrict__ eidx,
                                              const float4* __restrict__ c4,
                                              int* __restrict__ deg,
                                              unsigned int* __restrict__ emll) {
    int e = blockIdx.x * 256 + threadIdx.x;     // exactly NE
    int r = eidx[e];
    int c = eidx[NE + e];
    float4 pr = c4[r], pc = c4[c];
    float dx = pr.x - pc.x, dy = pr.y - pc.y, dz = pr.z - pc.z;
    float d = sqrtf(dx * dx + dy * dy + dz * dz);
    float u = d * ((float)(NB - 1) / DMAXT);
    int b = (int)(u + 0.5f);
    if (b > NB - 1) b = NB - 1;
    unsigned int em = (unsigned int)c | ((unsigned int)b << 16);
    int pos = atomicAdd(&deg[r], 1);
    if (pos < ELLS) emll[r * ELLS + pos] = em;
}

// LDS-staged MFMA GEMM: Out[M,128](bf16) = A(bf16) @ BT^T (+Cin bf16)(+bias f32).
__global__ __launch_bounds__(256) void k_gemm(const unsigned short* __restrict__ A,
                                              const unsigned short* __restrict__ BT,
                                              const unsigned short* __restrict__ Cin,
                                              const float* __restrict__ bias,
                                              unsigned short* __restrict__ Out,
                                              int M) {
    __shared__ unsigned short Als[64 * ASTR];    // 17.4 KB
    __shared__ unsigned short Bls[128 * ASTR];   // 34.8 KB
    int tx = threadIdx.x;
    int row0 = blockIdx.x * 64;
    #pragma unroll
    for (int q = 0; q < 4; ++q) {
        int l = tx + q * 256;
        int r = l >> 4, c = l & 15;
        int grow = row0 + r;
        uint4 v = make_uint4(0u, 0u, 0u, 0u);
        if (grow < M) v = *(const uint4*)(A + (size_t)grow * 128 + c * 8);
        *(uint4*)(&Als[r * ASTR + c * 8]) = v;
    }
    #pragma unroll
    for (int q = 0; q < 8; ++q) {
        int l = tx + q * 256;
        int r = l >> 4, c = l & 15;
        *(uint4*)(&Bls[r * ASTR + c * 8]) = *(const uint4*)(BT + (size_t)r * 128 + c * 8);
    }
    __syncthreads();

    int w = tx >> 6, lane = tx & 63, m = lane & 15, quad = lane >> 4;
    f32x4 acc[8];
    #pragma unroll
    for (int ct = 0; ct < 8; ++ct) acc[ct] = (f32x4){0.f, 0.f, 0.f, 0.f};
    #pragma unroll
    for (int s = 0; s < 4; ++s) {
        bf16x8 a = *(const bf16x8*)(&Als[(w * 16 + m) * ASTR + s * 32 + quad * 8]);
        #pragma unroll
        for (int ct = 0; ct < 8; ++ct) {
            bf16x8 b = *(const bf16x8*)(&Bls[(ct * 16 + m) * ASTR + s * 32 + quad * 8]);
            acc[ct] = __builtin_amdgcn_mfma_f32_16x16x32_bf16(a, b, acc[ct], 0, 0, 0);
        }
    }
    #pragma unroll
    for (int r = 0; r < 4; ++r) {
        int grow = row0 + w * 16 + quad * 4 + r;
        if (grow >= M) continue;
        #pragma unroll
        for (int ct = 0; ct < 8; ++ct) {
            int col = ct * 16 + m;
            float v = acc[ct][r];
            if (bias) v += bias[col];
            if (Cin)  v += bf2f(Cin[(size_t)grow * 128 + col]);
            Out[(size_t)grow * 128 + col] = f2bf(v);
        }
    }
}

// One wave per node: out[i,:] = sum_j t[col_j,:] * Tb[bin_j,:] (+ addin[i,:]).
// Per edge: 1 shfl + 4B t-gather + 4B packed-bf16 table load + 2 FMA.
__global__ __launch_bounds__(256) void k_agg(const unsigned short* __restrict__ t,
                                             const unsigned int* __restrict__ Tb,
                                             const int* __restrict__ deg,
                                             const unsigned int* __restrict__ emll,
                                             const unsigned short* __restrict__ addin,
                                             unsigned short* __restrict__ outb) {
    int wave = (blockIdx.x * blockDim.x + threadIdx.x) >> 6;
    int lane = threadIdx.x & 63;
    if (wave >= NN) return;
    int dg = min(deg[wave], ELLS);
    int dgp = (dg + 7) & ~7;
    const int base = wave * ELLS;
    const unsigned short* tl = t + 2 * lane;
    const unsigned int* Tl = Tb + lane;
    float ax = 0.f, ay = 0.f;
    if (addin) {   // hoisted: issues early, overlaps the gather loop
        unsigned int av = *(const unsigned int*)(addin + (size_t)wave * FD + 2 * lane);
        ax = asf(av << 16);
        ay = asf(av & 0xFFFF0000u);
    }
    for (int j0 = 0; j0 < dgp; j0 += 64) {
        int n = min(64, dgp - j0);
        unsigned int myem = SENT;
        if (lane < dg - j0) myem = emll[base + j0 + lane];
        for (int j = 0; j < n; j += 8) {
            #pragma unroll
            for (int u = 0; u < 8; ++u) {
                unsigned int em = (unsigned int)__shfl((int)myem, j + u, 64);
                int c = em & 0xFFFF;
                int b = em >> 16;
                unsigned int tvv = *(const unsigned int*)(tl + (size_t)c * HD);
                unsigned int q = Tl[(size_t)b * 64];
                ax = fmaf(asf(tvv << 16), asf(q << 16), ax);
                ay = fmaf(asf(tvv & 0xFFFF0000u), asf(q & 0xFFFF0000u), ay);
            }
        }
    }
    unsigned int o = (unsigned int)f2bf(ax) | ((unsigned int)f2bf(ay) << 16);
    *(unsigned int*)(outb + (size_t)wave * FD + 2 * lane) = o;
}

// Readout: G1 = asum@w_h + hg[charge[row]] + gvec; p = ssp(G1)@w_g2 + b_g2.
// batch is SORTED: block-level segmented scan -> ~1 atomic per graph per
// block instead of 64 (50k atomics onto 32 lines was ~50us of fabric serial).
__global__ __launch_bounds__(256) void k_readout(const unsigned short* __restrict__ asum,
                                                 const int* __restrict__ charges,
                                                 const int* __restrict__ batch,
                                                 const unsigned short* __restrict__ whT,
                                                 const unsigned short* __restrict__ hg,
                                                 const float* __restrict__ gvec,
                                                 const float* __restrict__ w_g2,
                                                 const float* __restrict__ b_g2,
                                                 float* __restrict__ out) {
    __shared__ unsigned short Als[64 * ASTR];
    __shared__ unsigned short Bls[64 * ASTR];
    __shared__ float pbuf[64];
    __shared__ int bbuf[64];
    int tx = threadIdx.x;
    int row0 = blockIdx.x * 64;
    #pragma unroll
    for (int q = 0; q < 4; ++q) {
        int l = tx + q * 256;
        int r = l >> 4, c = l & 15;
        int grow = row0 + r;
        uint4 v = make_uint4(0u, 0u, 0u, 0u);
        if (grow < NN) v = *(const uint4*)(asum + (size_t)grow * 128 + c * 8);
        *(uint4*)(&Als[r * ASTR + c * 8]) = v;
    }
    #pragma unroll
    for (int q = 0; q < 4; ++q) {
        int l = tx + q * 256;
        int r = l >> 4, c = l & 15;
        *(uint4*)(&Bls[r * ASTR + c * 8]) = *(const uint4*)(whT + (size_t)r * 128 + c * 8);
    }
    __syncthreads();

    int w = tx >> 6, lane = tx & 63, m = lane & 15, quad = lane >> 4;
    f32x4 acc[4];
    #pragma unroll
    for (int ct = 0; ct < 4; ++ct) acc[ct] = (f32x4){0.f, 0.f, 0.f, 0.f};
    #pragma unroll
    for (int s = 0; s < 4; ++s) {
        bf16x8 a = *(const bf16x8*)(&Als[(w * 16 + m) * ASTR + s * 32 + quad * 8]);
        #pragma unroll
        for (int ct = 0; ct < 4; ++ct) {
            bf16x8 b = *(const bf16x8*)(&Bls[(ct * 16 + m) * ASTR + s * 32 + quad * 8]);
            acc[ct] = __builtin_amdgcn_mfma_f32_16x16x32_bf16(a, b, acc[ct], 0, 0, 0);
        }
    }
    float gv[4], w2[4];
    #pragma unroll
    for (int ct = 0; ct < 4; ++ct) {
        int col = ct * 16 + m;
        gv[ct] = gvec[col];
        w2[ct] = w_g2[col];
    }
    float bg2 = b_g2[0];
    #pragma unroll
    for (int r = 0; r < 4; ++r) {
        int row = row0 + w * 16 + quad * 4 + r;
        int rowc = row < NN ? row : NN - 1;
        int ch = charges[rowc];
        float p = 0.f;
        #pragma unroll
        for (int ct = 0; ct < 4; ++ct) {
            int col = ct * 16 + m;
            float g1 = acc[ct][r] + bf2f(hg[ch * 64 + col]) + gv[ct];
            p += sspf(g1) * w2[ct];
        }
        p += __shfl_down(p, 8, 16);
        p += __shfl_down(p, 4, 16);
        p += __shfl_down(p, 2, 16);
        p += __shfl_down(p, 1, 16);
        if (m == 0) {
            int loc = w * 16 + quad * 4 + r;
            pbuf[loc] = p + bg2;
            bbuf[loc] = (row < NN) ? batch[row] : -1;
        }
    }
    __syncthreads();
    if (tx < 64) {   // wave 0: segmented inclusive scan over 64 rows
        float v = pbuf[tx];
        int b = bbuf[tx];
        #pragma unroll
        for (int off = 1; off < 64; off <<= 1) {
            float vo = __shfl_up(v, off, 64);
            int bo = __shfl_up(b, off, 64);
            if (tx >= off && bo == b) v += vo;
        }
        int bn = __shfl_down(b, 1, 64);
        bool seglast = (tx == 63) || (bn != b);
        if (seglast && b >= 0) atomicAdd(&out[b], v);
    }
}

extern "C" void kernel_launch(void* const* d_in, const int* in_sizes, int n_in,
                              void* d_out, int out_size, void* d_ws, size_t ws_size,
                              hipStream_t stream) {
    const int*   charges = (const int*)d_in[0];
    const float* coords  = (const float*)d_in[1];
    const int*   eidx    = (const int*)d_in[2];
    const int*   batch   = (const int*)d_in[3];
    const float* emb     = (const float*)d_in[4];
    const float* w_e1    = (const float*)d_in[5];
    const float* b_e1    = (const float*)d_in[6];
    const float* w_e2    = (const float*)d_in[7];
    const float* b_e2    = (const float*)d_in[8];
    const float* w_el    = (const float*)d_in[9];
    const float* w_nm    = (const float*)d_in[10];
    const float* b_nm    = (const float*)d_in[11];
    const float* w_g1    = (const float*)d_in[12];
    const float* b_g1    = (const float*)d_in[13];
    const float* w_g2    = (const float*)d_in[14];
    const float* b_g2    = (const float*)d_in[15];
    float* out = (float*)d_out;

    char* ws = (char*)d_ws;
    size_t off = 0;
    auto alloc = [&](size_t bytes) -> char* {
        char* p = ws + off;
        off += (bytes + 255) & ~(size_t)255;
        return p;
    };
    unsigned short* t1   = (unsigned short*)alloc((size_t)(NN + 1) * HD * 2); // +sentinel
    unsigned short* t2   = (unsigned short*)alloc((size_t)(NN + 1) * HD * 2); // +sentinel
    unsigned short* agg1 = (unsigned short*)alloc((size_t)NN * FD * 2);
    unsigned short* asum = (unsigned short*)alloc((size_t)NN * FD * 2);
    unsigned int*   Tb   = (unsigned int*)alloc((size_t)NB * 64 * 4);         // 1 MB
    int*            deg  = (int*)alloc((size_t)NN * 4);
    unsigned int*   emll = (unsigned int*)alloc((size_t)NN * ELLS * 4);       // 16 MB
    unsigned short* wfT  = (unsigned short*)alloc((size_t)128 * 128 * 2);
    unsigned short* whT  = (unsigned short*)alloc((size_t)64 * 128 * 2);
    unsigned short* tv   = (unsigned short*)alloc((size_t)VOCAB * 128 * 2);
    unsigned short* hg   = (unsigned short*)alloc((size_t)VOCAB * 64 * 2);
    float*          bv   = (float*)alloc(128 * 4);
    float*          gvec = (float*)alloc(64 * 4);
    float4*         c4   = (float4*)alloc((size_t)NN * 16);
    if (off > ws_size) return;  // workspace too small -> fail visibly, no OOB

    k_prep<<<TB_B + WF_B + WH_B + TV_B + HG_B + BV_B + C4_B + Z_B, 128, 0, stream>>>(
        w_e1, b_e1, w_e2, b_e2, w_el, w_nm, b_nm, w_g1, b_g1, emb, coords,
        Tb, wfT, whT, tv, hg, bv, gvec, c4, deg, out,
        (unsigned int*)(t1 + (size_t)NN * HD),
        (unsigned int*)(t2 + (size_t)NN * HD));
    k_t1<<<NN * 16 / 256, 256, 0, stream>>>(charges, tv, t1);
    k_edge<<<NE / 256, 256, 0, stream>>>(eidx, c4, deg, emll);

    // agg1 = AGG(t1)
    k_agg<<<NN / 4, 256, 0, stream>>>(t1, Tb, deg, emll, nullptr, agg1);
    // t2 = t1 + agg1 @ w_f + b_nm@w_el
    k_gemm<<<(NN + 63) / 64, 256, 0, stream>>>(agg1, wfT, t1, bv, t2, NN);
    // asum = agg1 + AGG(t2)
    k_agg<<<NN / 4, 256, 0, stream>>>(t2, Tb, deg, emll, agg1, asum);

    k_readout<<<(NN + 63) / 64, 256, 0, stream>>>(asum, charges, batch, whT, hg,
                                                  gvec, w_g2, b_g2, out);
}

// Round 15
// 259.437 us; speedup vs baseline: 1.3341x; 1.0038x over previous
//
#include <hip/hip_runtime.h>
#include <hip/hip_bf16.h>

// SchNet forward on MI355X.
// W(d) -> 4096-bin nearest-neighbor bf16-packed table; ELL (packed col|bin)
// for atomic-free segment sum; telescoped linear residual (composed weights);
// bf16 MFMA GEMM; bf16 data plane; sorted-batch segmented-scan readout.
// R15: table build restructured. R14's prep ran 4096 scalar blocks each
//      re-streaming 64KB w_e2 (~268MB L2). Now prep emits Y = bf16(ssp(
//      gauss@w_e1+b_e1)) at 4 bins/block (w_e1 register-reused 4x), and the
//      layer-2 matmul Tb = Y@w_e2 + b_e2 is one 64-block MFMA k_gemm call
//      (bf16 row layout == packed-uint table layout agg reads; no repack).

#define NN 50000      // nodes
#define NE 800000     // edges
#define NGR 512       // graphs
#define HD 128        // hidden
#define FD 128        // filters
#define GG 50         // gaussians
#define VOCAB 100
#define NB 4096       // table bins (nearest-neighbor)
#define DMAXT 12.0f   // table covers [0,12]
#define ELLS 80       // ELL stride; deg ~ Poisson(16)
#define SENT 50000u   // sentinel col -> zeroed extra row of t1/t2 (bin 0)
#define ASTR 136      // LDS row stride in bf16 elems

#define DELTA (10.0f/49.0f)
#define COEFF (-0.5f/(DELTA*DELTA))

// k_prep grid segments
#define TBY_B 1024    // Y = ssp(gauss@w_e1+b_e1), 4 bins/block
#define WE2T_B 128
#define WF_B 128
#define WH_B 64
#define TV_B 100
#define HG_B 100
#define BV_B 2
#define C4_B 391
#define Z_B  396      // ceil((NN+NGR+64+64)/128)

typedef __attribute__((ext_vector_type(8))) short bf16x8;
typedef __attribute__((ext_vector_type(4))) float f32x4;

static __device__ __forceinline__ float sspf(float x) {
    return fmaxf(x, 0.0f) + log1pf(expf(-fabsf(x))) - 0.69314718055994531f;
}
static __device__ __forceinline__ float asf(unsigned int u) {
    union { unsigned int u; float f; } v; v.u = u; return v.f;
}
static __device__ __forceinline__ float bf2f(unsigned short b) {
    union { unsigned int u; float f; } v; v.u = ((unsigned int)b) << 16; return v.f;
}
static __device__ __forceinline__ unsigned short f2bf(float f) {
    union { float f; unsigned int u; } v; v.f = f;
    unsigned int r = v.u + 0x7FFF + ((v.u >> 16) & 1);   // round-nearest-even
    return (unsigned short)(r >> 16);
}

// Fused prep (segments by blockIdx.x): Y table stage-1; we2T; wfT=(w_nm@w_el)^T;
// whT=(w_nm@w_g1)^T; tv=emb@w_el; hg=emb@w_g1; bv=b_nm@w_el,
// gvec=b_g1+2*b_nm@w_g1; coords->float4; zero deg/out/t1-/t2-sentinels.
__global__ __launch_bounds__(128) void k_prep(const float* __restrict__ w_e1,
                                              const float* __restrict__ b_e1,
                                              const float* __restrict__ w_e2,
                                              const float* __restrict__ w_el,
                                              const float* __restrict__ w_nm,
                                              const float* __restrict__ b_nm,
                                              const float* __restrict__ w_g1,
                                              const float* __restrict__ b_g1,
                                              const float* __restrict__ emb,
                                              const float* __restrict__ coords,
                                              unsigned short* __restrict__ Ytab,
                                              unsigned short* __restrict__ we2T,
                                              unsigned short* __restrict__ wfT,
                                              unsigned short* __restrict__ whT,
                                              unsigned short* __restrict__ tv,
                                              unsigned short* __restrict__ hg,
                                              float* __restrict__ bv,
                                              float* __restrict__ gvec,
                                              float4* __restrict__ c4,
                                              int* __restrict__ deg,
                                              float* __restrict__ out,
                                              unsigned int* __restrict__ t1s,
                                              unsigned int* __restrict__ t2s) {
    __shared__ float sbuf[256];
    int bid = blockIdx.x, tx = threadIdx.x;
    if (bid < TBY_B) {
        int bin0 = bid * 4;
        #pragma unroll
        for (int b = 0; b < 4; ++b) {
            if (tx < GG) {
                float d = (float)(bin0 + b) * (DMAXT / (float)(NB - 1));
                float tt = d - (float)tx * DELTA;
                sbuf[b * 64 + tx] = expf(COEFF * tt * tt);
            }
        }
        __syncthreads();
        float be = b_e1[tx];
        float a0 = be, a1 = be, a2 = be, a3 = be;
        #pragma unroll 10
        for (int g = 0; g < GG; ++g) {
            float w = w_e1[g * FD + tx];
            a0 = fmaf(sbuf[g], w, a0);
            a1 = fmaf(sbuf[64 + g], w, a1);
            a2 = fmaf(sbuf[128 + g], w, a2);
            a3 = fmaf(sbuf[192 + g], w, a3);
        }
        Ytab[(size_t)(bin0 + 0) * 128 + tx] = f2bf(sspf(a0));
        Ytab[(size_t)(bin0 + 1) * 128 + tx] = f2bf(sspf(a1));
        Ytab[(size_t)(bin0 + 2) * 128 + tx] = f2bf(sspf(a2));
        Ytab[(size_t)(bin0 + 3) * 128 + tx] = f2bf(sspf(a3));
    } else if (bid < TBY_B + WE2T_B) {
        int n = bid - TBY_B;
        we2T[n * 128 + tx] = f2bf(w_e2[tx * 128 + n]);   // [n][k]
    } else if (bid < TBY_B + WE2T_B + WF_B) {
        int n = bid - TBY_B - WE2T_B;
        sbuf[tx] = w_el[tx * 128 + n];
        __syncthreads();
        float acc = 0.f;
        #pragma unroll 8
        for (int j = 0; j < 128; ++j) acc = fmaf(w_nm[tx * 128 + j], sbuf[j], acc);
        wfT[n * 128 + tx] = f2bf(acc);
    } else if (bid < TBY_B + WE2T_B + WF_B + WH_B) {
        int n = bid - TBY_B - WE2T_B - WF_B;              // output col (0..63)
        sbuf[tx] = w_g1[tx * 64 + n];
        __syncthreads();
        float acc = 0.f;
        #pragma unroll 8
        for (int j = 0; j < 128; ++j) acc = fmaf(w_nm[tx * 128 + j], sbuf[j], acc);
        whT[n * 128 + tx] = f2bf(acc);                    // [n][k] B-fragment layout
    } else if (bid < TBY_B + WE2T_B + WF_B + WH_B + TV_B) {
        int r = bid - TBY_B - WE2T_B - WF_B - WH_B;
        sbuf[tx] = emb[r * HD + tx];
        __syncthreads();
        float acc = 0.f;
        #pragma unroll 8
        for (int k = 0; k < HD; ++k) acc = fmaf(sbuf[k], w_el[k * FD + tx], acc);
        tv[r * FD + tx] = f2bf(acc);
    } else if (bid < TBY_B + WE2T_B + WF_B + WH_B + TV_B + HG_B) {
        int c = bid - TBY_B - WE2T_B - WF_B - WH_B - TV_B;
        sbuf[tx] = emb[c * HD + tx];
        __syncthreads();
        if (tx < 64) {
            float acc = 0.f;
            #pragma unroll 8
            for (int k = 0; k < HD; ++k) acc = fmaf(sbuf[k], w_g1[k * 64 + tx], acc);
            hg[c * 64 + tx] = f2bf(acc);
        }
    } else if (bid < TBY_B + WE2T_B + WF_B + WH_B + TV_B + HG_B + BV_B) {
        int which = bid - (TBY_B + WE2T_B + WF_B + WH_B + TV_B + HG_B);
        if (which == 0) {
            float acc = 0.f;
            for (int k = 0; k < HD; ++k) acc = fmaf(b_nm[k], w_el[k * FD + tx], acc);
            bv[tx] = acc;
        } else if (tx < 64) {
            float acc = 0.f;
            for (int k = 0; k < HD; ++k) acc = fmaf(b_nm[k], w_g1[k * 64 + tx], acc);
            gvec[tx] = b_g1[tx] + 2.0f * acc;
        }
    } else if (bid < TBY_B + WE2T_B + WF_B + WH_B + TV_B + HG_B + BV_B + C4_B) {
        int i = (bid - (TBY_B + WE2T_B + WF_B + WH_B + TV_B + HG_B + BV_B)) * 128 + tx;
        if (i < NN)
            c4[i] = make_float4(coords[3 * i], coords[3 * i + 1],
                                coords[3 * i + 2], 0.f);
    } else {
        int j = (bid - (TBY_B + WE2T_B + WF_B + WH_B + TV_B + HG_B + BV_B + C4_B)) * 128 + tx;
        if (j < NN) deg[j] = 0;
        else if (j < NN + NGR) out[j - NN] = 0.f;
        else if (j < NN + NGR + 64) t1s[j - NN - NGR] = 0u;
        else if (j < NN + NGR + 128) t2s[j - NN - NGR - 64] = 0u;
    }
}

// t1[i] = tv[charges[i]]  (pure streaming gather from 25.6KB hot table)
__global__ __launch_bounds__(256) void k_t1(const int* __restrict__ charges,
                                            const unsigned short* __restrict__ tv,
                                            unsigned short* __restrict__ t1) {
    int idx = blockIdx.x * 256 + threadIdx.x;   // exactly NN*16 uint4s
    int i = idx >> 4;
    int f = idx & 15;
    int c = charges[i];
    ((uint4*)t1)[(size_t)i * 16 + f] = ((const uint4*)tv)[(size_t)c * 16 + f];
}

// Edge bucketing: pack (col 16b | bin 12b) into ELL slot of row.
__global__ __launch_bounds__(256) void k_edge(const int* __restrict__ eidx,
                                              const float4* __restrict__ c4,
                                              int* __restrict__ deg,
                                              unsigned int* __restrict__ emll) {
    int e = blockIdx.x * 256 + threadIdx.x;     // exactly NE
    int r = eidx[e];
    int c = eidx[NE + e];
    float4 pr = c4[r], pc = c4[c];
    float dx = pr.x - pc.x, dy = pr.y - pc.y, dz = pr.z - pc.z;
    float d = sqrtf(dx * dx + dy * dy + dz * dz);
    float u = d * ((float)(NB - 1) / DMAXT);
    int b = (int)(u + 0.5f);
    if (b > NB - 1) b = NB - 1;
    unsigned int em = (unsigned int)c | ((unsigned int)b << 16);
    int pos = atomicAdd(&deg[r], 1);
    if (pos < ELLS) emll[r * ELLS + pos] = em;
}

// LDS-staged MFMA GEMM: Out[M,128](bf16) = A(bf16) @ BT^T (+Cin bf16)(+bias f32).
__global__ __launch_bounds__(256) void k_gemm(const unsigned short* __restrict__ A,
                                              const unsigned short* __restrict__ BT,
                                              const unsigned short* __restrict__ Cin,
                                              const float* __restrict__ bias,
                                              unsigned short* __restrict__ Out,
                                              int M) {
    __shared__ unsigned short Als[64 * ASTR];    // 17.4 KB
    __shared__ unsigned short Bls[128 * ASTR];   // 34.8 KB
    int tx = threadIdx.x;
    int row0 = blockIdx.x * 64;
    #pragma unroll
    for (int q = 0; q < 4; ++q) {
        int l = tx + q * 256;
        int r = l >> 4, c = l & 15;
        int grow = row0 + r;
        uint4 v = make_uint4(0u, 0u, 0u, 0u);
        if (grow < M) v = *(const uint4*)(A + (size_t)grow * 128 + c * 8);
        *(uint4*)(&Als[r * ASTR + c * 8]) = v;
    }
    #pragma unroll
    for (int q = 0; q < 8; ++q) {
        int l = tx + q * 256;
        int r = l >> 4, c = l & 15;
        *(uint4*)(&Bls[r * ASTR + c * 8]) = *(const uint4*)(BT + (size_t)r * 128 + c * 8);
    }
    __syncthreads();

    int w = tx >> 6, lane = tx & 63, m = lane & 15, quad = lane >> 4;
    f32x4 acc[8];
    #pragma unroll
    for (int ct = 0; ct < 8; ++ct) acc[ct] = (f32x4){0.f, 0.f, 0.f, 0.f};
    #pragma unroll
    for (int s = 0; s < 4; ++s) {
        bf16x8 a = *(const bf16x8*)(&Als[(w * 16 + m) * ASTR + s * 32 + quad * 8]);
        #pragma unroll
        for (int ct = 0; ct < 8; ++ct) {
            bf16x8 b = *(const bf16x8*)(&Bls[(ct * 16 + m) * ASTR + s * 32 + quad * 8]);
            acc[ct] = __builtin_amdgcn_mfma_f32_16x16x32_bf16(a, b, acc[ct], 0, 0, 0);
        }
    }
    #pragma unroll
    for (int r = 0; r < 4; ++r) {
        int grow = row0 + w * 16 + quad * 4 + r;
        if (grow >= M) continue;
        #pragma unroll
        for (int ct = 0; ct < 8; ++ct) {
            int col = ct * 16 + m;
            float v = acc[ct][r];
            if (bias) v += bias[col];
            if (Cin)  v += bf2f(Cin[(size_t)grow * 128 + col]);
            Out[(size_t)grow * 128 + col] = f2bf(v);
        }
    }
}

// One wave per node: out[i,:] = sum_j t[col_j,:] * Tb[bin_j,:] (+ addin[i,:]).
// Per edge: 1 shfl + 4B t-gather + 4B packed-bf16 table load + 2 FMA.
__global__ __launch_bounds__(256) void k_agg(const unsigned short* __restrict__ t,
                                             const unsigned int* __restrict__ Tb,
                                             const int* __restrict__ deg,
                                             const unsigned int* __restrict__ emll,
                                             const unsigned short* __restrict__ addin,
                                             unsigned short* __restrict__ outb) {
    int wave = (blockIdx.x * blockDim.x + threadIdx.x) >> 6;
    int lane = threadIdx.x & 63;
    if (wave >= NN) return;
    int dg = min(deg[wave], ELLS);
    int dgp = (dg + 7) & ~7;
    const int base = wave * ELLS;
    const unsigned short* tl = t + 2 * lane;
    const unsigned int* Tl = Tb + lane;
    float ax = 0.f, ay = 0.f;
    if (addin) {   // hoisted: issues early, overlaps the gather loop
        unsigned int av = *(const unsigned int*)(addin + (size_t)wave * FD + 2 * lane);
        ax = asf(av << 16);
        ay = asf(av & 0xFFFF0000u);
    }
    for (int j0 = 0; j0 < dgp; j0 += 64) {
        int n = min(64, dgp - j0);
        unsigned int myem = SENT;
        if (lane < dg - j0) myem = emll[base + j0 + lane];
        for (int j = 0; j < n; j += 8) {
            #pragma unroll
            for (int u = 0; u < 8; ++u) {
                unsigned int em = (unsigned int)__shfl((int)myem, j + u, 64);
                int c = em & 0xFFFF;
                int b = em >> 16;
                unsigned int tvv = *(const unsigned int*)(tl + (size_t)c * HD);
                unsigned int q = Tl[(size_t)b * 64];
                ax = fmaf(asf(tvv << 16), asf(q << 16), ax);
                ay = fmaf(asf(tvv & 0xFFFF0000u), asf(q & 0xFFFF0000u), ay);
            }
        }
    }
    unsigned int o = (unsigned int)f2bf(ax) | ((unsigned int)f2bf(ay) << 16);
    *(unsigned int*)(outb + (size_t)wave * FD + 2 * lane) = o;
}

// Readout: G1 = asum@w_h + hg[charge[row]] + gvec; p = ssp(G1)@w_g2 + b_g2.
// batch is SORTED: block-level segmented scan -> ~1 atomic per graph per block.
__global__ __launch_bounds__(256) void k_readout(const unsigned short* __restrict__ asum,
                                                 const int* __restrict__ charges,
                                                 const int* __restrict__ batch,
                                                 const unsigned short* __restrict__ whT,
                                                 const unsigned short* __restrict__ hg,
                                                 const float* __restrict__ gvec,
                                                 const float* __restrict__ w_g2,
                                                 const float* __restrict__ b_g2,
                                                 float* __restrict__ out) {
    __shared__ unsigned short Als[64 * ASTR];
    __shared__ unsigned short Bls[64 * ASTR];
    __shared__ float pbuf[64];
    __shared__ int bbuf[64];
    int tx = threadIdx.x;
    int row0 = blockIdx.x * 64;
    #pragma unroll
    for (int q = 0; q < 4; ++q) {
        int l = tx + q * 256;
        int r = l >> 4, c = l & 15;
        int grow = row0 + r;
        uint4 v = make_uint4(0u, 0u, 0u, 0u);
        if (grow < NN) v = *(const uint4*)(asum + (size_t)grow * 128 + c * 8);
        *(uint4*)(&Als[r * ASTR + c * 8]) = v;
    }
    #pragma unroll
    for (int q = 0; q < 4; ++q) {
        int l = tx + q * 256;
        int r = l >> 4, c = l & 15;
        *(uint4*)(&Bls[r * ASTR + c * 8]) = *(const uint4*)(whT + (size_t)r * 128 + c * 8);
    }
    __syncthreads();

    int w = tx >> 6, lane = tx & 63, m = lane & 15, quad = lane >> 4;
    f32x4 acc[4];
    #pragma unroll
    for (int ct = 0; ct < 4; ++ct) acc[ct] = (f32x4){0.f, 0.f, 0.f, 0.f};
    #pragma unroll
    for (int s = 0; s < 4; ++s) {
        bf16x8 a = *(const bf16x8*)(&Als[(w * 16 + m) * ASTR + s * 32 + quad * 8]);
        #pragma unroll
        for (int ct = 0; ct < 4; ++ct) {
            bf16x8 b = *(const bf16x8*)(&Bls[(ct * 16 + m) * ASTR + s * 32 + quad * 8]);
            acc[ct] = __builtin_amdgcn_mfma_f32_16x16x32_bf16(a, b, acc[ct], 0, 0, 0);
        }
    }
    float gv[4], w2[4];
    #pragma unroll
    for (int ct = 0; ct < 4; ++ct) {
        int col = ct * 16 + m;
        gv[ct] = gvec[col];
        w2[ct] = w_g2[col];
    }
    float bg2 = b_g2[0];
    #pragma unroll
    for (int r = 0; r < 4; ++r) {
        int row = row0 + w * 16 + quad * 4 + r;
        int rowc = row < NN ? row : NN - 1;
        int ch = charges[rowc];
        float p = 0.f;
        #pragma unroll
        for (int ct = 0; ct < 4; ++ct) {
            int col = ct * 16 + m;
            float g1 = acc[ct][r] + bf2f(hg[ch * 64 + col]) + gv[ct];
            p += sspf(g1) * w2[ct];
        }
        p += __shfl_down(p, 8, 16);
        p += __shfl_down(p, 4, 16);
        p += __shfl_down(p, 2, 16);
        p += __shfl_down(p, 1, 16);
        if (m == 0) {
            int loc = w * 16 + quad * 4 + r;
            pbuf[loc] = p + bg2;
            bbuf[loc] = (row < NN) ? batch[row] : -1;
        }
    }
    __syncthreads();
    if (tx < 64) {   // wave 0: segmented inclusive scan over 64 rows
        float v = pbuf[tx];
        int b = bbuf[tx];
        #pragma unroll
        for (int off = 1; off < 64; off <<= 1) {
            float vo = __shfl_up(v, off, 64);
            int bo = __shfl_up(b, off, 64);
            if (tx >= off && bo == b) v += vo;
        }
        int bn = __shfl_down(b, 1, 64);
        bool seglast = (tx == 63) || (bn != b);
        if (seglast && b >= 0) atomicAdd(&out[b], v);
    }
}

extern "C" void kernel_launch(void* const* d_in, const int* in_sizes, int n_in,
                              void* d_out, int out_size, void* d_ws, size_t ws_size,
                              hipStream_t stream) {
    const int*   charges = (const int*)d_in[0];
    const float* coords  = (const float*)d_in[1];
    const int*   eidx    = (const int*)d_in[2];
    const int*   batch   = (const int*)d_in[3];
    const float* emb     = (const float*)d_in[4];
    const float* w_e1    = (const float*)d_in[5];
    const float* b_e1    = (const float*)d_in[6];
    const float* w_e2    = (const float*)d_in[7];
    const float* b_e2    = (const float*)d_in[8];
    const float* w_el    = (const float*)d_in[9];
    const float* w_nm    = (const float*)d_in[10];
    const float* b_nm    = (const float*)d_in[11];
    const float* w_g1    = (const float*)d_in[12];
    const float* b_g1    = (const float*)d_in[13];
    const float* w_g2    = (const float*)d_in[14];
    const float* b_g2    = (const float*)d_in[15];
    float* out = (float*)d_out;

    char* ws = (char*)d_ws;
    size_t off = 0;
    auto alloc = [&](size_t bytes) -> char* {
        char* p = ws + off;
        off += (bytes + 255) & ~(size_t)255;
        return p;
    };
    unsigned short* t1   = (unsigned short*)alloc((size_t)(NN + 1) * HD * 2); // +sentinel
    unsigned short* t2   = (unsigned short*)alloc((size_t)(NN + 1) * HD * 2); // +sentinel
    unsigned short* agg1 = (unsigned short*)alloc((size_t)NN * FD * 2);
    unsigned short* asum = (unsigned short*)alloc((size_t)NN * FD * 2);
    unsigned int*   Tb   = (unsigned int*)alloc((size_t)NB * 64 * 4);         // 1 MB
    unsigned short* Ytab = (unsigned short*)alloc((size_t)NB * 128 * 2);      // 1 MB
    int*            deg  = (int*)alloc((size_t)NN * 4);
    unsigned int*   emll = (unsigned int*)alloc((size_t)NN * ELLS * 4);       // 16 MB
    unsigned short* we2T = (unsigned short*)alloc((size_t)128 * 128 * 2);
    unsigned short* wfT  = (unsigned short*)alloc((size_t)128 * 128 * 2);
    unsigned short* whT  = (unsigned short*)alloc((size_t)64 * 128 * 2);
    unsigned short* tv   = (unsigned short*)alloc((size_t)VOCAB * 128 * 2);
    unsigned short* hg   = (unsigned short*)alloc((size_t)VOCAB * 64 * 2);
    float*          bv   = (float*)alloc(128 * 4);
    float*          gvec = (float*)alloc(64 * 4);
    float4*         c4   = (float4*)alloc((size_t)NN * 16);
    if (off > ws_size) return;  // workspace too small -> fail visibly, no OOB

    k_prep<<<TBY_B + WE2T_B + WF_B + WH_B + TV_B + HG_B + BV_B + C4_B + Z_B, 128, 0, stream>>>(
        w_e1, b_e1, w_e2, w_el, w_nm, b_nm, w_g1, b_g1, emb, coords,
        Ytab, we2T, wfT, whT, tv, hg, bv, gvec, c4, deg, out,
        (unsigned int*)(t1 + (size_t)NN * HD),
        (unsigned int*)(t2 + (size_t)NN * HD));
    // Tb = Y @ w_e2 + b_e2  (bf16 rows == packed-uint layout)
    k_gemm<<<NB / 64, 256, 0, stream>>>(Ytab, we2T, nullptr, b_e2,
                                        (unsigned short*)Tb, NB);
    k_t1<<<NN * 16 / 256, 256, 0, stream>>>(charges, tv, t1);
    k_edge<<<NE / 256, 256, 0, stream>>>(eidx, c4, deg, emll);

    // agg1 = AGG(t1)
    k_agg<<<NN / 4, 256, 0, stream>>>(t1, Tb, deg, emll, nullptr, agg1);
    // t2 = t1 + agg1 @ w_f + b_nm@w_el
    k_gemm<<<(NN + 63) / 64, 256, 0, stream>>>(agg1, wfT, t1, bv, t2, NN);
    // asum = agg1 + AGG(t2)
    k_agg<<<NN / 4, 256, 0, stream>>>(t2, Tb, deg, emll, agg1, asum);

    k_readout<<<(NN + 63) / 64, 256, 0, stream>>>(asum, charges, batch, whT, hg,
                                                  gvec, w_g2, b_g2, out);
}

// Round 16
// 258.353 us; speedup vs baseline: 1.3397x; 1.0042x over previous
//
#include <hip/hip_runtime.h>
#include <hip/hip_bf16.h>

// SchNet forward on MI355X.
// W(d) -> 4096-bin nearest-neighbor bf16-packed table; ELL (packed col|bin)
// for atomic-free segment sum; telescoped linear residual (composed weights);
// bf16 MFMA GEMM; bf16 data plane; sorted-batch segmented-scan readout.
// R16: (a) agg inner unroll 8->16 (32 outstanding gathers/wave, no new
//      dependent loads); (b) t1 gather folded into k_edge grid (both
//      LDS-free latency-bound kernels; edge VALU is 1.5% idle) -> one fewer
//      dispatch. Rest identical to R15 (259us).

#define NN 50000      // nodes
#define NE 800000     // edges
#define NGR 512       // graphs
#define HD 128        // hidden
#define FD 128        // filters
#define GG 50         // gaussians
#define VOCAB 100
#define NB 4096       // table bins (nearest-neighbor)
#define DMAXT 12.0f   // table covers [0,12]
#define ELLS 80       // ELL stride; deg ~ Poisson(16)
#define SENT 50000u   // sentinel col -> zeroed extra row of t1/t2 (bin 0)
#define ASTR 136      // LDS row stride in bf16 elems

#define DELTA (10.0f/49.0f)
#define COEFF (-0.5f/(DELTA*DELTA))

// k_prep grid segments
#define TBY_B 1024    // Y = ssp(gauss@w_e1+b_e1), 4 bins/block
#define WE2T_B 128
#define WF_B 128
#define WH_B 64
#define TV_B 100
#define HG_B 100
#define BV_B 2
#define C4_B 391
#define Z_B  396      // ceil((NN+NGR+64+64)/128)
// k_edge grid segments
#define EDGB 3125     // NE/256
#define T1B  3125     // NN*16/256

typedef __attribute__((ext_vector_type(8))) short bf16x8;
typedef __attribute__((ext_vector_type(4))) float f32x4;

static __device__ __forceinline__ float sspf(float x) {
    return fmaxf(x, 0.0f) + log1pf(expf(-fabsf(x))) - 0.69314718055994531f;
}
static __device__ __forceinline__ float asf(unsigned int u) {
    union { unsigned int u; float f; } v; v.u = u; return v.f;
}
static __device__ __forceinline__ float bf2f(unsigned short b) {
    union { unsigned int u; float f; } v; v.u = ((unsigned int)b) << 16; return v.f;
}
static __device__ __forceinline__ unsigned short f2bf(float f) {
    union { float f; unsigned int u; } v; v.f = f;
    unsigned int r = v.u + 0x7FFF + ((v.u >> 16) & 1);   // round-nearest-even
    return (unsigned short)(r >> 16);
}

// Fused prep (segments by blockIdx.x): Y table stage-1; we2T; wfT=(w_nm@w_el)^T;
// whT=(w_nm@w_g1)^T; tv=emb@w_el; hg=emb@w_g1; bv=b_nm@w_el,
// gvec=b_g1+2*b_nm@w_g1; coords->float4; zero deg/out/t1-/t2-sentinels.
__global__ __launch_bounds__(128) void k_prep(const float* __restrict__ w_e1,
                                              const float* __restrict__ b_e1,
                                              const float* __restrict__ w_e2,
                                              const float* __restrict__ w_el,
                                              const float* __restrict__ w_nm,
                                              const float* __restrict__ b_nm,
                                              const float* __restrict__ w_g1,
                                              const float* __restrict__ b_g1,
                                              const float* __restrict__ emb,
                                              const float* __restrict__ coords,
                                              unsigned short* __restrict__ Ytab,
                                              unsigned short* __restrict__ we2T,
                                              unsigned short* __restrict__ wfT,
                                              unsigned short* __restrict__ whT,
                                              unsigned short* __restrict__ tv,
                                              unsigned short* __restrict__ hg,
                                              float* __restrict__ bv,
                                              float* __restrict__ gvec,
                                              float4* __restrict__ c4,
                                              int* __restrict__ deg,
                                              float* __restrict__ out,
                                              unsigned int* __restrict__ t1s,
                                              unsigned int* __restrict__ t2s) {
    __shared__ float sbuf[256];
    int bid = blockIdx.x, tx = threadIdx.x;
    if (bid < TBY_B) {
        int bin0 = bid * 4;
        #pragma unroll
        for (int b = 0; b < 4; ++b) {
            if (tx < GG) {
                float d = (float)(bin0 + b) * (DMAXT / (float)(NB - 1));
                float tt = d - (float)tx * DELTA;
                sbuf[b * 64 + tx] = expf(COEFF * tt * tt);
            }
        }
        __syncthreads();
        float be = b_e1[tx];
        float a0 = be, a1 = be, a2 = be, a3 = be;
        #pragma unroll 10
        for (int g = 0; g < GG; ++g) {
            float w = w_e1[g * FD + tx];
            a0 = fmaf(sbuf[g], w, a0);
            a1 = fmaf(sbuf[64 + g], w, a1);
            a2 = fmaf(sbuf[128 + g], w, a2);
            a3 = fmaf(sbuf[192 + g], w, a3);
        }
        Ytab[(size_t)(bin0 + 0) * 128 + tx] = f2bf(sspf(a0));
        Ytab[(size_t)(bin0 + 1) * 128 + tx] = f2bf(sspf(a1));
        Ytab[(size_t)(bin0 + 2) * 128 + tx] = f2bf(sspf(a2));
        Ytab[(size_t)(bin0 + 3) * 128 + tx] = f2bf(sspf(a3));
    } else if (bid < TBY_B + WE2T_B) {
        int n = bid - TBY_B;
        we2T[n * 128 + tx] = f2bf(w_e2[tx * 128 + n]);   // [n][k]
    } else if (bid < TBY_B + WE2T_B + WF_B) {
        int n = bid - TBY_B - WE2T_B;
        sbuf[tx] = w_el[tx * 128 + n];
        __syncthreads();
        float acc = 0.f;
        #pragma unroll 8
        for (int j = 0; j < 128; ++j) acc = fmaf(w_nm[tx * 128 + j], sbuf[j], acc);
        wfT[n * 128 + tx] = f2bf(acc);
    } else if (bid < TBY_B + WE2T_B + WF_B + WH_B) {
        int n = bid - TBY_B - WE2T_B - WF_B;              // output col (0..63)
        sbuf[tx] = w_g1[tx * 64 + n];
        __syncthreads();
        float acc = 0.f;
        #pragma unroll 8
        for (int j = 0; j < 128; ++j) acc = fmaf(w_nm[tx * 128 + j], sbuf[j], acc);
        whT[n * 128 + tx] = f2bf(acc);                    // [n][k] B-fragment layout
    } else if (bid < TBY_B + WE2T_B + WF_B + WH_B + TV_B) {
        int r = bid - TBY_B - WE2T_B - WF_B - WH_B;
        sbuf[tx] = emb[r * HD + tx];
        __syncthreads();
        float acc = 0.f;
        #pragma unroll 8
        for (int k = 0; k < HD; ++k) acc = fmaf(sbuf[k], w_el[k * FD + tx], acc);
        tv[r * FD + tx] = f2bf(acc);
    } else if (bid < TBY_B + WE2T_B + WF_B + WH_B + TV_B + HG_B) {
        int c = bid - TBY_B - WE2T_B - WF_B - WH_B - TV_B;
        sbuf[tx] = emb[c * HD + tx];
        __syncthreads();
        if (tx < 64) {
            float acc = 0.f;
            #pragma unroll 8
            for (int k = 0; k < HD; ++k) acc = fmaf(sbuf[k], w_g1[k * 64 + tx], acc);
            hg[c * 64 + tx] = f2bf(acc);
        }
    } else if (bid < TBY_B + WE2T_B + WF_B + WH_B + TV_B + HG_B + BV_B) {
        int which = bid - (TBY_B + WE2T_B + WF_B + WH_B + TV_B + HG_B);
        if (which == 0) {
            float acc = 0.f;
            for (int k = 0; k < HD; ++k) acc = fmaf(b_nm[k], w_el[k * FD + tx], acc);
            bv[tx] = acc;
        } else if (tx < 64) {
            float acc = 0.f;
            for (int k = 0; k < HD; ++k) acc = fmaf(b_nm[k], w_g1[k * 64 + tx], acc);
            gvec[tx] = b_g1[tx] + 2.0f * acc;
        }
    } else if (bid < TBY_B + WE2T_B + WF_B + WH_B + TV_B + HG_B + BV_B + C4_B) {
        int i = (bid - (TBY_B + WE2T_B + WF_B + WH_B + TV_B + HG_B + BV_B)) * 128 + tx;
        if (i < NN)
            c4[i] = make_float4(coords[3 * i], coords[3 * i + 1],
                                coords[3 * i + 2], 0.f);
    } else {
        int j = (bid - (TBY_B + WE2T_B + WF_B + WH_B + TV_B + HG_B + BV_B + C4_B)) * 128 + tx;
        if (j < NN) deg[j] = 0;
        else if (j < NN + NGR) out[j - NN] = 0.f;
        else if (j < NN + NGR + 64) t1s[j - NN - NGR] = 0u;
        else if (j < NN + NGR + 128) t2s[j - NN - NGR - 64] = 0u;
    }
}

// Fused: [0,EDGB): edge bucketing (pack col|bin into ELL slot of row);
// [EDGB,+T1B): t1[i] = tv[charges[i]] streaming gather (fills edge's idle
// issue slots; both halves LDS-free).
__global__ __launch_bounds__(256) void k_edge(const int* __restrict__ eidx,
                                              const float4* __restrict__ c4,
                                              const int* __restrict__ charges,
                                              const unsigned short* __restrict__ tv,
                                              int* __restrict__ deg,
                                              unsigned int* __restrict__ emll,
                                              unsigned short* __restrict__ t1) {
    int bid = blockIdx.x, tx = threadIdx.x;
    if (bid < EDGB) {
        int e = bid * 256 + tx;                 // exactly NE
        int r = eidx[e];
        int c = eidx[NE + e];
        float4 pr = c4[r], pc = c4[c];
        float dx = pr.x - pc.x, dy = pr.y - pc.y, dz = pr.z - pc.z;
        float d = sqrtf(dx * dx + dy * dy + dz * dz);
        float u = d * ((float)(NB - 1) / DMAXT);
        int b = (int)(u + 0.5f);
        if (b > NB - 1) b = NB - 1;
        unsigned int em = (unsigned int)c | ((unsigned int)b << 16);
        int pos = atomicAdd(&deg[r], 1);
        if (pos < ELLS) emll[r * ELLS + pos] = em;
    } else {
        int idx = (bid - EDGB) * 256 + tx;      // exactly NN*16 uint4s
        int i = idx >> 4;
        int f = idx & 15;
        int c = charges[i];
        ((uint4*)t1)[(size_t)i * 16 + f] = ((const uint4*)tv)[(size_t)c * 16 + f];
    }
}

// LDS-staged MFMA GEMM: Out[M,128](bf16) = A(bf16) @ BT^T (+Cin bf16)(+bias f32).
__global__ __launch_bounds__(256) void k_gemm(const unsigned short* __restrict__ A,
                                              const unsigned short* __restrict__ BT,
                                              const unsigned short* __restrict__ Cin,
                                              const float* __restrict__ bias,
                                              unsigned short* __restrict__ Out,
                                              int M) {
    __shared__ unsigned short Als[64 * ASTR];    // 17.4 KB
    __shared__ unsigned short Bls[128 * ASTR];   // 34.8 KB
    int tx = threadIdx.x;
    int row0 = blockIdx.x * 64;
    #pragma unroll
    for (int q = 0; q < 4; ++q) {
        int l = tx + q * 256;
        int r = l >> 4, c = l & 15;
        int grow = row0 + r;
        uint4 v = make_uint4(0u, 0u, 0u, 0u);
        if (grow < M) v = *(const uint4*)(A + (size_t)grow * 128 + c * 8);
        *(uint4*)(&Als[r * ASTR + c * 8]) = v;
    }
    #pragma unroll
    for (int q = 0; q < 8; ++q) {
        int l = tx + q * 256;
        int r = l >> 4, c = l & 15;
        *(uint4*)(&Bls[r * ASTR + c * 8]) = *(const uint4*)(BT + (size_t)r * 128 + c * 8);
    }
    __syncthreads();

    int w = tx >> 6, lane = tx & 63, m = lane & 15, quad = lane >> 4;
    f32x4 acc[8];
    #pragma unroll
    for (int ct = 0; ct < 8; ++ct) acc[ct] = (f32x4){0.f, 0.f, 0.f, 0.f};
    #pragma unroll
    for (int s = 0; s < 4; ++s) {
        bf16x8 a = *(const bf16x8*)(&Als[(w * 16 + m) * ASTR + s * 32 + quad * 8]);
        #pragma unroll
        for (int ct = 0; ct < 8; ++ct) {
            bf16x8 b = *(const bf16x8*)(&Bls[(ct * 16 + m) * ASTR + s * 32 + quad * 8]);
            acc[ct] = __builtin_amdgcn_mfma_f32_16x16x32_bf16(a, b, acc[ct], 0, 0, 0);
        }
    }
    #pragma unroll
    for (int r = 0; r < 4; ++r) {
        int grow = row0 + w * 16 + quad * 4 + r;
        if (grow >= M) continue;
        #pragma unroll
        for (int ct = 0; ct < 8; ++ct) {
            int col = ct * 16 + m;
            float v = acc[ct][r];
            if (bias) v += bias[col];
            if (Cin)  v += bf2f(Cin[(size_t)grow * 128 + col]);
            Out[(size_t)grow * 128 + col] = f2bf(v);
        }
    }
}

#define AGG_BODY(JU)                                                          \
    {                                                                         \
        unsigned int em = (unsigned int)__shfl((int)myem, (JU), 64);          \
        int c = em & 0xFFFF;                                                  \
        int b = em >> 16;                                                     \
        unsigned int tvv = *(const unsigned int*)(tl + (size_t)c * HD);       \
        unsigned int q = Tl[(size_t)b * 64];                                  \
        ax = fmaf(asf(tvv << 16), asf(q << 16), ax);                          \
        ay = fmaf(asf(tvv & 0xFFFF0000u), asf(q & 0xFFFF0000u), ay);          \
    }

// One wave per node: out[i,:] = sum_j t[col_j,:] * Tb[bin_j,:] (+ addin[i,:]).
// 16x unroll (8-tail): ~32 outstanding gathers per wave.
__global__ __launch_bounds__(256) void k_agg(const unsigned short* __restrict__ t,
                                             const unsigned int* __restrict__ Tb,
                                             const int* __restrict__ deg,
                                             const unsigned int* __restrict__ emll,
                                             const unsigned short* __restrict__ addin,
                                             unsigned short* __restrict__ outb) {
    int wave = (blockIdx.x * blockDim.x + threadIdx.x) >> 6;
    int lane = threadIdx.x & 63;
    if (wave >= NN) return;
    int dg = min(deg[wave], ELLS);
    int dgp = (dg + 7) & ~7;
    const int base = wave * ELLS;
    const unsigned short* tl = t + 2 * lane;
    const unsigned int* Tl = Tb + lane;
    float ax = 0.f, ay = 0.f;
    if (addin) {   // hoisted: issues early, overlaps the gather loop
        unsigned int av = *(const unsigned int*)(addin + (size_t)wave * FD + 2 * lane);
        ax = asf(av << 16);
        ay = asf(av & 0xFFFF0000u);
    }
    for (int j0 = 0; j0 < dgp; j0 += 64) {
        int n = min(64, dgp - j0);
        unsigned int myem = SENT;
        if (lane < dg - j0) myem = emll[base + j0 + lane];
        int j = 0;
        for (; j + 16 <= n; j += 16) {
            #pragma unroll
            for (int u = 0; u < 16; ++u) AGG_BODY(j + u)
        }
        if (j < n) {
            #pragma unroll
            for (int u = 0; u < 8; ++u) AGG_BODY(j + u)
        }
    }
    unsigned int o = (unsigned int)f2bf(ax) | ((unsigned int)f2bf(ay) << 16);
    *(unsigned int*)(outb + (size_t)wave * FD + 2 * lane) = o;
}

// Readout: G1 = asum@w_h + hg[charge[row]] + gvec; p = ssp(G1)@w_g2 + b_g2.
// batch is SORTED: block-level segmented scan -> ~1 atomic per graph per block.
__global__ __launch_bounds__(256) void k_readout(const unsigned short* __restrict__ asum,
                                                 const int* __restrict__ charges,
                                                 const int* __restrict__ batch,
                                                 const unsigned short* __restrict__ whT,
                                                 const unsigned short* __restrict__ hg,
                                                 const float* __restrict__ gvec,
                                                 const float* __restrict__ w_g2,
                                                 const float* __restrict__ b_g2,
                                                 float* __restrict__ out) {
    __shared__ unsigned short Als[64 * ASTR];
    __shared__ unsigned short Bls[64 * ASTR];
    __shared__ float pbuf[64];
    __shared__ int bbuf[64];
    int tx = threadIdx.x;
    int row0 = blockIdx.x * 64;
    #pragma unroll
    for (int q = 0; q < 4; ++q) {
        int l = tx + q * 256;
        int r = l >> 4, c = l & 15;
        int grow = row0 + r;
        uint4 v = make_uint4(0u, 0u, 0u, 0u);
        if (grow < NN) v = *(const uint4*)(asum + (size_t)grow * 128 + c * 8);
        *(uint4*)(&Als[r * ASTR + c * 8]) = v;
    }
    #pragma unroll
    for (int q = 0; q < 4; ++q) {
        int l = tx + q * 256;
        int r = l >> 4, c = l & 15;
        *(uint4*)(&Bls[r * ASTR + c * 8]) = *(const uint4*)(whT + (size_t)r * 128 + c * 8);
    }
    __syncthreads();

    int w = tx >> 6, lane = tx & 63, m = lane & 15, quad = lane >> 4;
    f32x4 acc[4];
    #pragma unroll
    for (int ct = 0; ct < 4; ++ct) acc[ct] = (f32x4){0.f, 0.f, 0.f, 0.f};
    #pragma unroll
    for (int s = 0; s < 4; ++s) {
        bf16x8 a = *(const bf16x8*)(&Als[(w * 16 + m) * ASTR + s * 32 + quad * 8]);
        #pragma unroll
        for (int ct = 0; ct < 4; ++ct) {
            bf16x8 b = *(const bf16x8*)(&Bls[(ct * 16 + m) * ASTR + s * 32 + quad * 8]);
            acc[ct] = __builtin_amdgcn_mfma_f32_16x16x32_bf16(a, b, acc[ct], 0, 0, 0);
        }
    }
    float gv[4], w2[4];
    #pragma unroll
    for (int ct = 0; ct < 4; ++ct) {
        int col = ct * 16 + m;
        gv[ct] = gvec[col];
        w2[ct] = w_g2[col];
    }
    float bg2 = b_g2[0];
    #pragma unroll
    for (int r = 0; r < 4; ++r) {
        int row = row0 + w * 16 + quad * 4 + r;
        int rowc = row < NN ? row : NN - 1;
        int ch = charges[rowc];
        float p = 0.f;
        #pragma unroll
        for (int ct = 0; ct < 4; ++ct) {
            int col = ct * 16 + m;
            float g1 = acc[ct][r] + bf2f(hg[ch * 64 + col]) + gv[ct];
            p += sspf(g1) * w2[ct];
        }
        p += __shfl_down(p, 8, 16);
        p += __shfl_down(p, 4, 16);
        p += __shfl_down(p, 2, 16);
        p += __shfl_down(p, 1, 16);
        if (m == 0) {
            int loc = w * 16 + quad * 4 + r;
            pbuf[loc] = p + bg2;
            bbuf[loc] = (row < NN) ? batch[row] : -1;
        }
    }
    __syncthreads();
    if (tx < 64) {   // wave 0: segmented inclusive scan over 64 rows
        float v = pbuf[tx];
        int b = bbuf[tx];
        #pragma unroll
        for (int off = 1; off < 64; off <<= 1) {
            float vo = __shfl_up(v, off, 64);
            int bo = __shfl_up(b, off, 64);
            if (tx >= off && bo == b) v += vo;
        }
        int bn = __shfl_down(b, 1, 64);
        bool seglast = (tx == 63) || (bn != b);
        if (seglast && b >= 0) atomicAdd(&out[b], v);
    }
}

extern "C" void kernel_launch(void* const* d_in, const int* in_sizes, int n_in,
                              void* d_out, int out_size, void* d_ws, size_t ws_size,
                              hipStream_t stream) {
    const int*   charges = (const int*)d_in[0];
    const float* coords  = (const float*)d_in[1];
    const int*   eidx    = (const int*)d_in[2];
    const int*   batch   = (const int*)d_in[3];
    const float* emb     = (const float*)d_in[4];
    const float* w_e1    = (const float*)d_in[5];
    const float* b_e1    = (const float*)d_in[6];
    const float* w_e2    = (const float*)d_in[7];
    const float* b_e2    = (const float*)d_in[8];
    const float* w_el    = (const float*)d_in[9];
    const float* w_nm    = (const float*)d_in[10];
    const float* b_nm    = (const float*)d_in[11];
    const float* w_g1    = (const float*)d_in[12];
    const float* b_g1    = (const float*)d_in[13];
    const float* w_g2    = (const float*)d_in[14];
    const float* b_g2    = (const float*)d_in[15];
    float* out = (float*)d_out;

    char* ws = (char*)d_ws;
    size_t off = 0;
    auto alloc = [&](size_t bytes) -> char* {
        char* p = ws + off;
        off += (bytes + 255) & ~(size_t)255;
        return p;
    };
    unsigned short* t1   = (unsigned short*)alloc((size_t)(NN + 1) * HD * 2); // +sentinel
    unsigned short* t2   = (unsigned short*)alloc((size_t)(NN + 1) * HD * 2); // +sentinel
    unsigned short* agg1 = (unsigned short*)alloc((size_t)NN * FD * 2);
    unsigned short* asum = (unsigned short*)alloc((size_t)NN * FD * 2);
    unsigned int*   Tb   = (unsigned int*)alloc((size_t)NB * 64 * 4);         // 1 MB
    unsigned short* Ytab = (unsigned short*)alloc((size_t)NB * 128 * 2);      // 1 MB
    int*            deg  = (int*)alloc((size_t)NN * 4);
    unsigned int*   emll = (unsigned int*)alloc((size_t)NN * ELLS * 4);       // 16 MB
    unsigned short* we2T = (unsigned short*)alloc((size_t)128 * 128 * 2);
    unsigned short* wfT  = (unsigned short*)alloc((size_t)128 * 128 * 2);
    unsigned short* whT  = (unsigned short*)alloc((size_t)64 * 128 * 2);
    unsigned short* tv   = (unsigned short*)alloc((size_t)VOCAB * 128 * 2);
    unsigned short* hg   = (unsigned short*)alloc((size_t)VOCAB * 64 * 2);
    float*          bv   = (float*)alloc(128 * 4);
    float*          gvec = (float*)alloc(64 * 4);
    float4*         c4   = (float4*)alloc((size_t)NN * 16);
    if (off > ws_size) return;  // workspace too small -> fail visibly, no OOB

    k_prep<<<TBY_B + WE2T_B + WF_B + WH_B + TV_B + HG_B + BV_B + C4_B + Z_B, 128, 0, stream>>>(
        w_e1, b_e1, w_e2, w_el, w_nm, b_nm, w_g1, b_g1, emb, coords,
        Ytab, we2T, wfT, whT, tv, hg, bv, gvec, c4, deg, out,
        (unsigned int*)(t1 + (size_t)NN * HD),
        (unsigned int*)(t2 + (size_t)NN * HD));
    // Tb = Y @ w_e2 + b_e2  (bf16 rows == packed-uint layout)
    k_gemm<<<NB / 64, 256, 0, stream>>>(Ytab, we2T, nullptr, b_e2,
                                        (unsigned short*)Tb, NB);
    // edge bucketing + t1 gather (fused grid)
    k_edge<<<EDGB + T1B, 256, 0, stream>>>(eidx, c4, charges, tv, deg, emll, t1);

    // agg1 = AGG(t1)
    k_agg<<<NN / 4, 256, 0, stream>>>(t1, Tb, deg, emll, nullptr, agg1);
    // t2 = t1 + agg1 @ w_f + b_nm@w_el
    k_gemm<<<(NN + 63) / 64, 256, 0, stream>>>(agg1, wfT, t1, bv, t2, NN);
    // asum = agg1 + AGG(t2)
    k_agg<<<NN / 4, 256, 0, stream>>>(t2, Tb, deg, emll, agg1, asum);

    k_readout<<<(NN + 63) / 64, 256, 0, stream>>>(asum, charges, batch, whT, hg,
                                                  gvec, w_g2, b_g2, out);
}